// Round 7
// baseline (296.326 us; speedup 1.0000x reference)
//
#include <hip/hip_runtime.h>
#include <stdint.h>

#define IMPOSSIBLE -10000.0f
#define TT 4096
#define NN 64
#define BB 64
#define CHUNK 128           // time-steps per chunk (R6-validated: 8 waves/CU)
#define WARM 32             // warm-up steps (Birkhoff contraction ~0.34/step -> ~1e-14)
#define KCH (TT / CHUNK)    // 32 chunks per sequence

// ---- bool-input dtype shim: harness may pass jnp.bool as int32 or uint8 ----
// mask[0][0..3] are always true (len >= T/2), so first word distinguishes:
//   uint8 layout -> 0x01010101 ; int32 layout -> 0x00000001
__device__ __forceinline__ bool bools_are_i32(const void* mask) {
  return ((const unsigned int*)mask)[0] == 1u;
}
__device__ __forceinline__ int bget(const void* p, int idx, bool i32) {
  return i32 ? ((const int*)p)[idx] : (int)((const unsigned char*)p)[idx];
}

// ---- DPP wave-64 reductions (VALU only) ----
__device__ __forceinline__ float wave_max_f32(float x) {
  int t;
#define STEP(ctrl)                                                            \
  t = __builtin_amdgcn_update_dpp(__float_as_int(x), __float_as_int(x), ctrl, \
                                  0xf, 0xf, false);                           \
  x = fmaxf(x, __int_as_float(t));
  STEP(0x111) STEP(0x112) STEP(0x114) STEP(0x118) STEP(0x142) STEP(0x143)
#undef STEP
  return __int_as_float(__builtin_amdgcn_readlane(__float_as_int(x), 63));
}

__device__ __forceinline__ float wave_sum_f32(float x) {
  int t;
#define STEP(ctrl)                                                         \
  t = __builtin_amdgcn_update_dpp(0, __float_as_int(x), ctrl, 0xf, 0xf,    \
                                  true);                                   \
  x += __int_as_float(t);
  STEP(0x111) STEP(0x112) STEP(0x114) STEP(0x118) STEP(0x142) STEP(0x143)
#undef STEP
  return __int_as_float(__builtin_amdgcn_readlane(__float_as_int(x), 63));
}

__device__ __forceinline__ int wave_sum_i32(int x) {
  int t;
#define STEP(ctrl)                                                      \
  t = __builtin_amdgcn_update_dpp(0, x, ctrl, 0xf, 0xf, true);          \
  x += t;
  STEP(0x111) STEP(0x112) STEP(0x114) STEP(0x118) STEP(0x142) STEP(0x143)
#undef STEP
  return __builtin_amdgcn_readlane(x, 63);
}

__device__ __forceinline__ float wave_lse(float x) {
  float m = wave_max_f32(x);
  float s = wave_sum_f32(__expf(x - m));
  return m + __logf(s);
}

// full-wave rotate by one lane (DPP 0x13C = wave_ror:1; direction probed at
// runtime, see below -- works under either hardware convention)
__device__ __forceinline__ float wave_ror1_f32(float x) {
  int xi = __float_as_int(x);
  int r = __builtin_amdgcn_update_dpp(xi, xi, 0x13C, 0xf, 0xf, false);
  return __int_as_float(r);
}

__device__ __forceinline__ int bytesum4(unsigned int u) {
  return (int)((u * 0x01010101u) >> 24);  // bytes are 0/1, sum <= 4
}

// ---------------- z1: chunked forward recurrence, systolic-DPP matvec -------
// R6 numerics (log-space, exact per-step wave-max renorm, warm-up discard)
// with the LDS broadcast matvec replaced by a zero-DS DPP rotation:
//   p stays lane-resident; per step, rotate p across the wave (wave_ror:1)
//   and accumulate with a SKEWED ET register file:
//     etA[k][lane] = exp(trans[(lane-d*k)&63][lane])        (chain A)
//     etB[k][lane] = exp(trans[(lane-d*k+32)&63][lane])     (chain B, seeded
//                                                            by shfl_xor 32)
//   After k rotations v[lane] = p[(lane-d*k)&63], so fmaf(v, et[k], acc)
//   sums over all 64 rows exactly.  d in {1,63} is probed at runtime by
//   rotating the lane id once -- correct under either ror direction.
// R6 evidence: per-step cost scales superlinearly with waves/CU (DS+issue
// queuing), serial floor ~300-500cy. This removes ALL per-step DS ops
// (no lgkmcnt round-trip) at the cost of ~60 extra VALU movs.
__global__ __launch_bounds__(64, 2) void crf_z1(
    const float* __restrict__ em, const void* __restrict__ mask,
    const float* __restrict__ trans, const float* __restrict__ startv,
    const float* __restrict__ endv, const void* __restrict__ ftr,
    const void* __restrict__ fst, const void* __restrict__ fen,
    float* __restrict__ out) {
  const int lane = threadIdx.x;
  const int b = blockIdx.x >> 5;   // KCH == 32
  const int c = blockIdx.x & 31;
  const bool i32 = bools_are_i32(mask);

  // len[b] = sum(mask[b, :])
  int ls = 0;
  if (i32) {
    const uint4* mv = (const uint4*)((const int*)mask + (size_t)b * TT);
#pragma unroll
    for (int k = 0; k < 16; ++k) {               // 1024 uint4 = 4096 ints
      uint4 w = mv[k * 64 + lane];
      ls += (int)(w.x + w.y + w.z + w.w);
    }
  } else {
    const uint4* mv = (const uint4*)((const unsigned char*)mask + (size_t)b * TT);
#pragma unroll
    for (int k = 0; k < 4; ++k) {                // 256 uint4 = 4096 bytes
      uint4 w = mv[k * 64 + lane];
      ls += bytesum4(w.x) + bytesum4(w.y) + bytesum4(w.z) + bytesum4(w.w);
    }
  }
  const int len = wave_sum_i32(ls);

  const int cL = c * CHUNK;
  if (cL >= len) return;  // chunk entirely beyond sequence end (wave-uniform)
  const int e_c = min(cL + CHUNK - 1, len - 1);
  const bool has_end = (len <= cL + CHUNK);  // len-1 inside this chunk

  // ---- probe the ror direction: one ror of the lane id gives (lane-d)&63
  const int d =
      (lane - __builtin_amdgcn_update_dpp(0, lane, 0x13C, 0xf, 0xf, true)) & 63;

  // ---- skewed ET register file (64 f32 VGPRs), masked + exponentiated ----
  float etA[32], etB[32];
#pragma unroll
  for (int k = 0; k < 32; ++k) {
    int ra = (lane - d * k) & 63;     // &63 == mod 64 for two's complement
    int rb = (ra + 32) & 63;
    float ta = trans[ra * NN + lane];
    float tbv = trans[rb * NN + lane];
    if (bget(ftr, ra * NN + lane, i32)) ta = IMPOSSIBLE;
    if (bget(ftr, rb * NN + lane, i32)) tbv = IMPOSSIBLE;
    etA[k] = __expf(ta);              // exp(-10000) == 0: forbidden drops out
    etB[k] = __expf(tbv);
  }

  const float* emb = em + (size_t)b * TT * NN + lane;
  float n, S = 0.f;
  int tb;
  if (c == 0) {
    float sv = startv[lane];
    if (bget(fst, lane, i32)) sv = IMPOSSIBLE;
    n = sv + emb[0];
    tb = 1;
  } else {
    int tw = cL - WARM;
    n = emb[(size_t)tw * NN];  // arbitrary init; warm-up forgets it
    tb = tw + 1;
  }

  // depth-6 em prefetch ring: one load/iter, consumed 6 iters later; no
  // barrier and no lgkmcnt anywhere in the loop -> vmcnt never drains.
  float r0 = emb[(size_t)tb * NN];
  float r1 = emb[(size_t)min(tb + 1, TT - 1) * NN];
  float r2 = emb[(size_t)min(tb + 2, TT - 1) * NN];
  float r3 = emb[(size_t)min(tb + 3, TT - 1) * NN];
  float r4 = emb[(size_t)min(tb + 4, TT - 1) * NN];
  float r5 = emb[(size_t)min(tb + 5, TT - 1) * NN];

  for (int t = tb; t <= e_c; ++t) {
    float rn = emb[(size_t)min(t + 6, TT - 1) * NN];  // prefetch t+6
    float m = wave_max_f32(n);
    float p = __expf(n - m);
    // systolic matvec: s_j = sum_i p_i * ET[i][j], zero DS ops
    float vA = p;
    float vB = __shfl_xor(p, 32, 64);  // p[(lane-32)&63] == p[lane^32]
    float a0 = 0.f, a1 = 0.f, a2 = 0.f, a3 = 0.f;
#pragma unroll
    for (int k = 0; k < 32; ++k) {
      if (k & 1) {
        a1 = fmaf(vA, etA[k], a1);
        a3 = fmaf(vB, etB[k], a3);
      } else {
        a0 = fmaf(vA, etA[k], a0);
        a2 = fmaf(vB, etB[k], a2);
      }
      vA = wave_ror1_f32(vA);
      vB = wave_ror1_f32(vB);
    }
    float s = (a0 + a1) + (a2 + a3);
    n = __logf(s) + r0;
    S += m;
    r0 = r1; r1 = r2; r2 = r3; r3 = r4; r4 = r5; r5 = rn;
    if (c > 0 && t == cL - 1) S = -wave_lse(n);  // discard warm-up scale
  }

  float ev = endv[lane];
  if (bget(fen, lane, i32)) ev = IMPOSSIBLE;
  float zc = has_end ? wave_lse(n + ev) : wave_lse(n);
  if (lane == 0) atomicAdd(out + b, S + zc);
}

// ---------------- z0: gold-path score, wave-per-row ballot version ----------
// (unchanged: ~12 us under the overhead model)
__global__ __launch_bounds__(256) void crf_z0(
    const float* __restrict__ em, const void* __restrict__ mask,
    const void* __restrict__ target, const float* __restrict__ trans,
    const float* __restrict__ startv, const float* __restrict__ endv,
    const void* __restrict__ ftr, const void* __restrict__ fst,
    const void* __restrict__ fen, float* __restrict__ out) {
  const int tid = threadIdx.x;
  const int lane = tid & 63;
  const int w = tid >> 6;
  const int b = blockIdx.x >> 4;
  const int q = blockIdx.x & 15;
  const bool i32 = bools_are_i32(mask);

  __shared__ int lred[4];
  __shared__ int tags[257];
  __shared__ float fred4[4];

  // ---- block-wide len[b] = sum(mask[b,:]) ----
  int ls = 0;
  if (i32) {
    const uint4* mv = (const uint4*)((const int*)mask + (size_t)b * TT);
#pragma unroll
    for (int k = 0; k < 4; ++k) {   // 1024 uint4 = 4096 ints
      uint4 u = mv[k * 256 + tid];
      ls += (int)(u.x + u.y + u.z + u.w);
    }
  } else {
    uint4 u = ((const uint4*)((const unsigned char*)mask + (size_t)b * TT))[tid];
    ls = bytesum4(u.x) + bytesum4(u.y) + bytesum4(u.z) + bytesum4(u.w);
  }
  ls = wave_sum_i32(ls);
  if (lane == 0) lred[w] = ls;

  // ---- tag extraction: wave w scans rows t0 + w*64 .. +63 ----
  const int t0 = q * 256;
  int mytag = 0;
  const size_t rb = ((size_t)b * TT + t0 + (size_t)w * 64) * NN + lane;
  if (i32) {
    const int* tg = (const int*)target + rb;
    for (int k = 0; k < 8; ++k) {
      int v[8];
#pragma unroll
      for (int j = 0; j < 8; ++j) v[j] = tg[(size_t)(k * 8 + j) * NN];
#pragma unroll
      for (int j = 0; j < 8; ++j) {
        unsigned long long bm = __ballot(v[j] != 0);
        int tv = __ffsll(bm) - 1;
        if (lane == k * 8 + j) mytag = tv;
      }
    }
  } else {
    const unsigned char* tg = (const unsigned char*)target + rb;
    for (int k = 0; k < 8; ++k) {
      int v[8];
#pragma unroll
      for (int j = 0; j < 8; ++j) v[j] = (int)tg[(size_t)(k * 8 + j) * NN];
#pragma unroll
      for (int j = 0; j < 8; ++j) {
        unsigned long long bm = __ballot(v[j] != 0);
        int tv = __ffsll(bm) - 1;
        if (lane == k * 8 + j) mytag = tv;
      }
    }
  }
  tags[tid + 1] = mytag;
  if (w == 0) {  // boundary row t0-1 for the block's first transition
    int rp = (t0 == 0) ? 0 : t0 - 1;
    int vv = i32 ? ((const int*)target)[((size_t)b * TT + rp) * NN + lane]
                 : (int)((const unsigned char*)
                       target)[((size_t)b * TT + rp) * NN + lane];
    unsigned long long bm = __ballot(vv != 0);
    int tv = __ffsll(bm) - 1;
    if (tid == 0) tags[0] = (t0 == 0) ? 0 : tv;
  }
  __syncthreads();  // publish lred + tags
  const int len = lred[0] + lred[1] + lred[2] + lred[3];

  const int t = t0 + tid;
  float contrib = 0.f;
  if (t < len) {
    int tg = tags[tid + 1];
    float emv = em[((size_t)b * TT + t) * NN + tg];
    if (t == 0) {
      float sv = startv[tg];
      if (bget(fst, tg, i32)) sv = IMPOSSIBLE;
      contrib = sv + emv;
    } else {
      int tp = tags[tid];
      float tv = trans[tp * NN + tg];
      if (bget(ftr, tp * NN + tg, i32)) tv = IMPOSSIBLE;
      contrib = tv + emv;
    }
    if (t == len - 1) {
      float evv = endv[tg];
      if (bget(fen, tg, i32)) evv = IMPOSSIBLE;
      contrib += evv;
    }
  }
  float wsum = wave_sum_f32(contrib);
  if (lane == 0) fred4[w] = wsum;
  __syncthreads();
  if (tid == 0)
    atomicAdd(out + b, -(fred4[0] + fred4[1] + fred4[2] + fred4[3]));
}

extern "C" void kernel_launch(void* const* d_in, const int* in_sizes, int n_in,
                              void* d_out, int out_size, void* d_ws,
                              size_t ws_size, hipStream_t stream) {
  const float* em = (const float*)d_in[0];
  const void* mask = d_in[1];
  const void* target = d_in[2];
  const float* trans = (const float*)d_in[3];
  const float* startv = (const float*)d_in[4];
  const float* endv = (const float*)d_in[5];
  const void* ftr = d_in[6];
  const void* fst = d_in[7];
  const void* fen = d_in[8];
  float* out = (float*)d_out;

  hipMemsetAsync(out, 0, BB * sizeof(float), stream);
  crf_z1<<<dim3(BB * KCH), dim3(64), 0, stream>>>(em, mask, trans, startv,
                                                  endv, ftr, fst, fen, out);
  crf_z0<<<dim3(BB * 16), dim3(256), 0, stream>>>(
      em, mask, target, trans, startv, endv, ftr, fst, fen, out);
}

// Round 8
// 249.132 us; speedup vs baseline: 1.1894x; 1.1894x over previous
//
#include <hip/hip_runtime.h>
#include <stdint.h>

#define IMPOSSIBLE -10000.0f
#define TT 4096
#define NN 64
#define BB 64
#define CHUNK 128           // time-steps per chunk (R6-validated: 8 waves/CU)
#define WARM 32             // warm-up steps (Birkhoff contraction ~0.34/step -> ~1e-14)
#define KCH (TT / CHUNK)    // 32 chunks per sequence

// ---- bool-input dtype shim: harness may pass jnp.bool as int32 or uint8 ----
// mask[0][0..3] are always true (len >= T/2), so first word distinguishes:
//   uint8 layout -> 0x01010101 ; int32 layout -> 0x00000001
__device__ __forceinline__ bool bools_are_i32(const void* mask) {
  return ((const unsigned int*)mask)[0] == 1u;
}
__device__ __forceinline__ int bget(const void* p, int idx, bool i32) {
  return i32 ? ((const int*)p)[idx] : (int)((const unsigned char*)p)[idx];
}

// ---- DPP wave-64 reductions (VALU only) ----
__device__ __forceinline__ float wave_max_f32(float x) {
  int t;
#define STEP(ctrl)                                                            \
  t = __builtin_amdgcn_update_dpp(__float_as_int(x), __float_as_int(x), ctrl, \
                                  0xf, 0xf, false);                           \
  x = fmaxf(x, __int_as_float(t));
  STEP(0x111) STEP(0x112) STEP(0x114) STEP(0x118) STEP(0x142) STEP(0x143)
#undef STEP
  return __int_as_float(__builtin_amdgcn_readlane(__float_as_int(x), 63));
}

__device__ __forceinline__ float wave_sum_f32(float x) {
  int t;
#define STEP(ctrl)                                                         \
  t = __builtin_amdgcn_update_dpp(0, __float_as_int(x), ctrl, 0xf, 0xf,    \
                                  true);                                   \
  x += __int_as_float(t);
  STEP(0x111) STEP(0x112) STEP(0x114) STEP(0x118) STEP(0x142) STEP(0x143)
#undef STEP
  return __int_as_float(__builtin_amdgcn_readlane(__float_as_int(x), 63));
}

__device__ __forceinline__ int wave_sum_i32(int x) {
  int t;
#define STEP(ctrl)                                                      \
  t = __builtin_amdgcn_update_dpp(0, x, ctrl, 0xf, 0xf, true);          \
  x += t;
  STEP(0x111) STEP(0x112) STEP(0x114) STEP(0x118) STEP(0x142) STEP(0x143)
#undef STEP
  return __builtin_amdgcn_readlane(x, 63);
}

__device__ __forceinline__ float wave_lse(float x) {
  float m = wave_max_f32(x);
  float s = wave_sum_f32(__expf(x - m));
  return m + __logf(s);
}

__device__ __forceinline__ int bytesum4(unsigned int u) {
  return (int)((u * 0x01010101u) >> 24);  // bytes are 0/1, sum <= 4
}

// ---------------- z1: chunked forward recurrence, readlane matvec -----------
// R6 numerics (log-space, exact per-step wave-max renorm, warm-up discard),
// matvec broadcast via v_readlane -> SGPR -> v_fmac_f32 (SGPR src0):
//   s_j = sum_i p_i * ET[i][j];  lane j holds column j of ET in 64 f32 VGPRs.
//   p_i is wave-uniform -> readlane(p, i) (64 INDEPENDENT VALU ops, no serial
//   chain, unlike R7's 64 dependent wave_ror DPPs) feeds fmac's SGPR slot.
// Removes ALL per-step DS ops (R6's queued resource at 8 waves/CU) without
// R7's serial-DPP latency wall. Per-step ~155 VALU instrs; the queued pipe
// is now the VALU itself (the right pipe to saturate).
__global__ __launch_bounds__(64, 2) void crf_z1(
    const float* __restrict__ em, const void* __restrict__ mask,
    const float* __restrict__ trans, const float* __restrict__ startv,
    const float* __restrict__ endv, const void* __restrict__ ftr,
    const void* __restrict__ fst, const void* __restrict__ fen,
    float* __restrict__ out) {
  const int lane = threadIdx.x;
  const int b = blockIdx.x >> 5;   // KCH == 32
  const int c = blockIdx.x & 31;
  const bool i32 = bools_are_i32(mask);

  // len[b] = sum(mask[b, :])
  int ls = 0;
  if (i32) {
    const uint4* mv = (const uint4*)((const int*)mask + (size_t)b * TT);
#pragma unroll
    for (int k = 0; k < 16; ++k) {               // 1024 uint4 = 4096 ints
      uint4 w = mv[k * 64 + lane];
      ls += (int)(w.x + w.y + w.z + w.w);
    }
  } else {
    const uint4* mv = (const uint4*)((const unsigned char*)mask + (size_t)b * TT);
#pragma unroll
    for (int k = 0; k < 4; ++k) {                // 256 uint4 = 4096 bytes
      uint4 w = mv[k * 64 + lane];
      ls += bytesum4(w.x) + bytesum4(w.y) + bytesum4(w.z) + bytesum4(w.w);
    }
  }
  const int len = wave_sum_i32(ls);

  const int cL = c * CHUNK;
  if (cL >= len) return;  // chunk entirely beyond sequence end (wave-uniform)
  const int e_c = min(cL + CHUNK - 1, len - 1);
  const bool has_end = (len <= cL + CHUNK);  // len-1 inside this chunk

  // ET column in registers: et[i] = exp(masked trans[i][lane]); 64 f32 VGPRs
  float et[64];
#pragma unroll
  for (int i = 0; i < 64; ++i) {
    float tv = trans[i * NN + lane];
    if (bget(ftr, i * NN + lane, i32)) tv = IMPOSSIBLE;
    et[i] = __expf(tv);               // exp(-10000) == 0: forbidden drops out
  }

  const float* emb = em + (size_t)b * TT * NN + lane;
  float n, S = 0.f;
  int tb;
  if (c == 0) {
    float sv = startv[lane];
    if (bget(fst, lane, i32)) sv = IMPOSSIBLE;
    n = sv + emb[0];
    tb = 1;
  } else {
    int tw = cL - WARM;
    n = emb[(size_t)tw * NN];  // arbitrary init; warm-up forgets it
    tb = tw + 1;
  }

  // depth-6 em prefetch ring: one load/iter, consumed 6 iters later; no
  // barrier, no DS op, no lgkmcnt anywhere in the loop -> vmcnt stays counted.
  float r0 = emb[(size_t)tb * NN];
  float r1 = emb[(size_t)min(tb + 1, TT - 1) * NN];
  float r2 = emb[(size_t)min(tb + 2, TT - 1) * NN];
  float r3 = emb[(size_t)min(tb + 3, TT - 1) * NN];
  float r4 = emb[(size_t)min(tb + 4, TT - 1) * NN];
  float r5 = emb[(size_t)min(tb + 5, TT - 1) * NN];

  for (int t = tb; t <= e_c; ++t) {
    float rn = emb[(size_t)min(t + 6, TT - 1) * NN];  // prefetch t+6
    float m = wave_max_f32(n);
    float p = __expf(n - m);
    const int pb = __float_as_int(p);
    // readlane matvec: 64 independent readlanes + 64 fmac (SGPR src), no DS
    float a0 = 0.f, a1 = 0.f, a2 = 0.f, a3 = 0.f;
#pragma unroll
    for (int k = 0; k < 16; ++k) {
      float s0 = __int_as_float(__builtin_amdgcn_readlane(pb, 4 * k + 0));
      float s1 = __int_as_float(__builtin_amdgcn_readlane(pb, 4 * k + 1));
      float s2 = __int_as_float(__builtin_amdgcn_readlane(pb, 4 * k + 2));
      float s3 = __int_as_float(__builtin_amdgcn_readlane(pb, 4 * k + 3));
      a0 = fmaf(s0, et[4 * k + 0], a0);
      a1 = fmaf(s1, et[4 * k + 1], a1);
      a2 = fmaf(s2, et[4 * k + 2], a2);
      a3 = fmaf(s3, et[4 * k + 3], a3);
    }
    float s = (a0 + a1) + (a2 + a3);
    n = __logf(s) + r0;
    S += m;
    r0 = r1; r1 = r2; r2 = r3; r3 = r4; r4 = r5; r5 = rn;
    if (c > 0 && t == cL - 1) S = -wave_lse(n);  // discard warm-up scale
  }

  float ev = endv[lane];
  if (bget(fen, lane, i32)) ev = IMPOSSIBLE;
  float zc = has_end ? wave_lse(n + ev) : wave_lse(n);
  if (lane == 0) atomicAdd(out + b, S + zc);
}

// ---------------- z0: gold-path score, wave-per-row ballot version ----------
// (unchanged: ~12 us under the overhead model)
__global__ __launch_bounds__(256) void crf_z0(
    const float* __restrict__ em, const void* __restrict__ mask,
    const void* __restrict__ target, const float* __restrict__ trans,
    const float* __restrict__ startv, const float* __restrict__ endv,
    const void* __restrict__ ftr, const void* __restrict__ fst,
    const void* __restrict__ fen, float* __restrict__ out) {
  const int tid = threadIdx.x;
  const int lane = tid & 63;
  const int w = tid >> 6;
  const int b = blockIdx.x >> 4;
  const int q = blockIdx.x & 15;
  const bool i32 = bools_are_i32(mask);

  __shared__ int lred[4];
  __shared__ int tags[257];
  __shared__ float fred4[4];

  // ---- block-wide len[b] = sum(mask[b,:]) ----
  int ls = 0;
  if (i32) {
    const uint4* mv = (const uint4*)((const int*)mask + (size_t)b * TT);
#pragma unroll
    for (int k = 0; k < 4; ++k) {   // 1024 uint4 = 4096 ints
      uint4 u = mv[k * 256 + tid];
      ls += (int)(u.x + u.y + u.z + u.w);
    }
  } else {
    uint4 u = ((const uint4*)((const unsigned char*)mask + (size_t)b * TT))[tid];
    ls = bytesum4(u.x) + bytesum4(u.y) + bytesum4(u.z) + bytesum4(u.w);
  }
  ls = wave_sum_i32(ls);
  if (lane == 0) lred[w] = ls;

  // ---- tag extraction: wave w scans rows t0 + w*64 .. +63 ----
  const int t0 = q * 256;
  int mytag = 0;
  const size_t rb = ((size_t)b * TT + t0 + (size_t)w * 64) * NN + lane;
  if (i32) {
    const int* tg = (const int*)target + rb;
    for (int k = 0; k < 8; ++k) {
      int v[8];
#pragma unroll
      for (int j = 0; j < 8; ++j) v[j] = tg[(size_t)(k * 8 + j) * NN];
#pragma unroll
      for (int j = 0; j < 8; ++j) {
        unsigned long long bm = __ballot(v[j] != 0);
        int tv = __ffsll(bm) - 1;
        if (lane == k * 8 + j) mytag = tv;
      }
    }
  } else {
    const unsigned char* tg = (const unsigned char*)target + rb;
    for (int k = 0; k < 8; ++k) {
      int v[8];
#pragma unroll
      for (int j = 0; j < 8; ++j) v[j] = (int)tg[(size_t)(k * 8 + j) * NN];
#pragma unroll
      for (int j = 0; j < 8; ++j) {
        unsigned long long bm = __ballot(v[j] != 0);
        int tv = __ffsll(bm) - 1;
        if (lane == k * 8 + j) mytag = tv;
      }
    }
  }
  tags[tid + 1] = mytag;
  if (w == 0) {  // boundary row t0-1 for the block's first transition
    int rp = (t0 == 0) ? 0 : t0 - 1;
    int vv = i32 ? ((const int*)target)[((size_t)b * TT + rp) * NN + lane]
                 : (int)((const unsigned char*)
                       target)[((size_t)b * TT + rp) * NN + lane];
    unsigned long long bm = __ballot(vv != 0);
    int tv = __ffsll(bm) - 1;
    if (tid == 0) tags[0] = (t0 == 0) ? 0 : tv;
  }
  __syncthreads();  // publish lred + tags
  const int len = lred[0] + lred[1] + lred[2] + lred[3];

  const int t = t0 + tid;
  float contrib = 0.f;
  if (t < len) {
    int tg = tags[tid + 1];
    float emv = em[((size_t)b * TT + t) * NN + tg];
    if (t == 0) {
      float sv = startv[tg];
      if (bget(fst, tg, i32)) sv = IMPOSSIBLE;
      contrib = sv + emv;
    } else {
      int tp = tags[tid];
      float tv = trans[tp * NN + tg];
      if (bget(ftr, tp * NN + tg, i32)) tv = IMPOSSIBLE;
      contrib = tv + emv;
    }
    if (t == len - 1) {
      float evv = endv[tg];
      if (bget(fen, tg, i32)) evv = IMPOSSIBLE;
      contrib += evv;
    }
  }
  float wsum = wave_sum_f32(contrib);
  if (lane == 0) fred4[w] = wsum;
  __syncthreads();
  if (tid == 0)
    atomicAdd(out + b, -(fred4[0] + fred4[1] + fred4[2] + fred4[3]));
}

extern "C" void kernel_launch(void* const* d_in, const int* in_sizes, int n_in,
                              void* d_out, int out_size, void* d_ws,
                              size_t ws_size, hipStream_t stream) {
  const float* em = (const float*)d_in[0];
  const void* mask = d_in[1];
  const void* target = d_in[2];
  const float* trans = (const float*)d_in[3];
  const float* startv = (const float*)d_in[4];
  const float* endv = (const float*)d_in[5];
  const void* ftr = d_in[6];
  const void* fst = d_in[7];
  const void* fen = d_in[8];
  float* out = (float*)d_out;

  hipMemsetAsync(out, 0, BB * sizeof(float), stream);
  crf_z1<<<dim3(BB * KCH), dim3(64), 0, stream>>>(em, mask, trans, startv,
                                                  endv, ftr, fst, fen, out);
  crf_z0<<<dim3(BB * 16), dim3(256), 0, stream>>>(
      em, mask, target, trans, startv, endv, ftr, fst, fen, out);
}

// Round 9
// 247.647 us; speedup vs baseline: 1.1966x; 1.0060x over previous
//
#include <hip/hip_runtime.h>
#include <stdint.h>

#define IMPOSSIBLE -10000.0f
#define TT 4096
#define NN 64
#define BB 64
#define CHUNK 128           // time-steps per chunk (R6-validated)
#define WARM 32             // warm-up steps (Birkhoff contraction ~0.34/step -> ~1e-14)
#define KCH (TT / CHUNK)    // 32 chunks per sequence
#define NI (WARM + CHUNK - 1)  // 159 unified iterations per wave

typedef _Float16 half2_t __attribute__((ext_vector_type(2)));

__device__ __forceinline__ float fdot2f(half2_t a, half2_t b, float c) {
#if __has_builtin(__builtin_amdgcn_fdot2)
  return __builtin_amdgcn_fdot2(a, b, c, false);
#else
  return c + (float)a[0] * (float)b[0] + (float)a[1] * (float)b[1];
#endif
}

// ---- bool-input dtype shim: harness may pass jnp.bool as int32 or uint8 ----
__device__ __forceinline__ bool bools_are_i32(const void* mask) {
  return ((const unsigned int*)mask)[0] == 1u;
}
__device__ __forceinline__ int bget(const void* p, int idx, bool i32) {
  return i32 ? ((const int*)p)[idx] : (int)((const unsigned char*)p)[idx];
}

// ---- DPP wave-64 reductions (VALU only) ----
__device__ __forceinline__ float wave_max_f32(float x) {
  int t;
#define STEP(ctrl)                                                            \
  t = __builtin_amdgcn_update_dpp(__float_as_int(x), __float_as_int(x), ctrl, \
                                  0xf, 0xf, false);                           \
  x = fmaxf(x, __int_as_float(t));
  STEP(0x111) STEP(0x112) STEP(0x114) STEP(0x118) STEP(0x142) STEP(0x143)
#undef STEP
  return __int_as_float(__builtin_amdgcn_readlane(__float_as_int(x), 63));
}

__device__ __forceinline__ float wave_sum_f32(float x) {
  int t;
#define STEP(ctrl)                                                         \
  t = __builtin_amdgcn_update_dpp(0, __float_as_int(x), ctrl, 0xf, 0xf,    \
                                  true);                                   \
  x += __int_as_float(t);
  STEP(0x111) STEP(0x112) STEP(0x114) STEP(0x118) STEP(0x142) STEP(0x143)
#undef STEP
  return __int_as_float(__builtin_amdgcn_readlane(__float_as_int(x), 63));
}

__device__ __forceinline__ int wave_sum_i32(int x) {
  int t;
#define STEP(ctrl)                                                      \
  t = __builtin_amdgcn_update_dpp(0, x, ctrl, 0xf, 0xf, true);          \
  x += t;
  STEP(0x111) STEP(0x112) STEP(0x114) STEP(0x118) STEP(0x142) STEP(0x143)
#undef STEP
  return __builtin_amdgcn_readlane(x, 63);
}

__device__ __forceinline__ float wave_lse(float x) {
  float m = wave_max_f32(x);
  float s = wave_sum_f32(__expf(x - m));
  return m + __logf(s);
}

__device__ __forceinline__ int bytesum4(unsigned int u) {
  return (int)((u * 0x01010101u) >> 24);  // bytes are 0/1, sum <= 4
}

// ---------------- z1: TWO chains per wave (ILP over the serial recurrence) --
// R8 falsified DS-queuing at 8 waves/CU (DS-free readlane variant was SLOWER:
// 110 vs 89us). The wall is the ~550cy serial chain (max->exp->DS round-trip->
// fdot->log) with only 2 waves/SIMD to overlap it. Fix: each wave advances
// TWO independent chunks -- cA = q (first half, always fully in-sequence
// since len >= T/2) and cB = q+16 (second half, possibly clipped by len).
// Their dependency chains interleave inside one wave; per-chain numerics are
// byte-identical to the verified R6 path (f16 pbuf/ET, fdot2, exact per-step
// renorm, warm-up discard at i==30). Chain exhaustion/inactivity handled by
// wave-uniform selects (no divergence); padded iterations are harmless.
__global__ __launch_bounds__(64, 1) void crf_z1(
    const float* __restrict__ em, const void* __restrict__ mask,
    const float* __restrict__ trans, const float* __restrict__ startv,
    const float* __restrict__ endv, const void* __restrict__ ftr,
    const void* __restrict__ fst, const void* __restrict__ fen,
    float* __restrict__ out) {
  const int lane = threadIdx.x;
  const int b = blockIdx.x >> 4;   // 16 chunk-pairs per batch
  const int q = blockIdx.x & 15;
  const bool i32 = bools_are_i32(mask);

  // len[b] = sum(mask[b, :])
  int ls = 0;
  if (i32) {
    const uint4* mv = (const uint4*)((const int*)mask + (size_t)b * TT);
#pragma unroll
    for (int k = 0; k < 16; ++k) {               // 1024 uint4 = 4096 ints
      uint4 w = mv[k * 64 + lane];
      ls += (int)(w.x + w.y + w.z + w.w);
    }
  } else {
    const uint4* mv = (const uint4*)((const unsigned char*)mask + (size_t)b * TT);
#pragma unroll
    for (int k = 0; k < 4; ++k) {                // 256 uint4 = 4096 bytes
      uint4 w = mv[k * 64 + lane];
      ls += bytesum4(w.x) + bytesum4(w.y) + bytesum4(w.z) + bytesum4(w.w);
    }
  }
  const int len = wave_sum_i32(ls);

  const int cA = q;              // chunk 0..15: cL+CHUNK <= 2048 <= len always
  const int cB = q + 16;         // chunk 16..31: may be partial or inactive
  const int LA = cA * CHUNK;
  const int LB = cB * CHUNK;
  const bool Bact = (LB < len);

  // ET[i][j] = exp(masked trans[i][j]); lane j holds column j as 32 f16 pairs
  half2_t et2[32];
#pragma unroll
  for (int i2 = 0; i2 < 32; ++i2) {
    int i0 = 2 * i2, i1 = 2 * i2 + 1;
    float t0 = trans[i0 * NN + lane];
    float t1 = trans[i1 * NN + lane];
    if (bget(ftr, i0 * NN + lane, i32)) t0 = IMPOSSIBLE;
    if (bget(ftr, i1 * NN + lane, i32)) t1 = IMPOSSIBLE;
    half2_t h;
    h[0] = (_Float16)__expf(t0);
    h[1] = (_Float16)__expf(t1);
    et2[i2] = h;
  }

  const float* emb = em + (size_t)b * TT * NN + lane;

  // chain A init
  float nA, SA = 0.f;
  int tloA;
  const int thiA = LA + CHUNK - 1;          // always <= len-1 (first half)
  if (cA == 0) {
    float sv = startv[lane];
    if (bget(fst, lane, i32)) sv = IMPOSSIBLE;
    nA = sv + emb[0];
    tloA = 1;
  } else {
    nA = emb[(size_t)(LA - WARM) * NN];     // arbitrary init; warm-up forgets
    tloA = LA - WARM + 1;
  }

  // chain B init (indices always memory-safe; results gated by Bact/thiB)
  float nB = emb[(size_t)(LB - WARM) * NN];
  float SB = 0.f;
  const int tloB = LB - WARM + 1;
  const int thiB = min(LB + CHUNK - 1, len - 1);  // < tloB when inactive

  __shared__ __align__(16) _Float16 pbuf[2][2][64];  // [chain][parity][64]

  // depth-4 em prefetch rings (one per chain); no barrier, vmcnt never drains
  float rA0 = emb[(size_t)tloA * NN];
  float rA1 = emb[(size_t)min(tloA + 1, TT - 1) * NN];
  float rA2 = emb[(size_t)min(tloA + 2, TT - 1) * NN];
  float rA3 = emb[(size_t)min(tloA + 3, TT - 1) * NN];
  float rB0 = emb[(size_t)tloB * NN];
  float rB1 = emb[(size_t)min(tloB + 1, TT - 1) * NN];
  float rB2 = emb[(size_t)min(tloB + 2, TT - 1) * NN];
  float rB3 = emb[(size_t)min(tloB + 3, TT - 1) * NN];

  for (int i = 0; i < NI; ++i) {
    const int tA = tloA + i;
    const int tB = tloB + i;
    float rnA = emb[(size_t)min(tA + 4, TT - 1) * NN];  // prefetch
    float rnB = emb[(size_t)min(tB + 4, TT - 1) * NN];

    // front halves (independent -> interleave)
    float mA = wave_max_f32(nA);
    float mB = wave_max_f32(nB);
    float pA = __expf(nA - mA);
    float pB = __expf(nB - mB);
    const int par = i & 1;
    pbuf[0][par][lane] = (_Float16)pA;
    pbuf[1][par][lane] = (_Float16)pB;
    asm volatile("s_waitcnt lgkmcnt(0)" ::: "memory");
    __builtin_amdgcn_sched_barrier(0);
    const uint4* pvA = (const uint4*)pbuf[0][par];
    const uint4* pvB = (const uint4*)pbuf[1][par];
    uint4 qaA[8], qaB[8];
#pragma unroll
    for (int k = 0; k < 8; ++k) qaA[k] = pvA[k];  // 16x ds_read_b128,
#pragma unroll
    for (int k = 0; k < 8; ++k) qaB[k] = pvB[k];  // one cluster
    __builtin_amdgcn_sched_barrier(0);
    float a0 = 0.f, a1 = 0.f, a2 = 0.f, a3 = 0.f;
    float b0 = 0.f, b1 = 0.f, b2 = 0.f, b3 = 0.f;
#pragma unroll
    for (int k = 0; k < 8; ++k) {
      a0 = fdot2f(__builtin_bit_cast(half2_t, qaA[k].x), et2[4 * k + 0], a0);
      a1 = fdot2f(__builtin_bit_cast(half2_t, qaA[k].y), et2[4 * k + 1], a1);
      a2 = fdot2f(__builtin_bit_cast(half2_t, qaA[k].z), et2[4 * k + 2], a2);
      a3 = fdot2f(__builtin_bit_cast(half2_t, qaA[k].w), et2[4 * k + 3], a3);
      b0 = fdot2f(__builtin_bit_cast(half2_t, qaB[k].x), et2[4 * k + 0], b0);
      b1 = fdot2f(__builtin_bit_cast(half2_t, qaB[k].y), et2[4 * k + 1], b1);
      b2 = fdot2f(__builtin_bit_cast(half2_t, qaB[k].z), et2[4 * k + 2], b2);
      b3 = fdot2f(__builtin_bit_cast(half2_t, qaB[k].w), et2[4 * k + 3], b3);
    }
    float sA = (a0 + a1) + (a2 + a3);
    float sB = (b0 + b1) + (b2 + b3);

    // act-gated updates (wave-uniform conditions -> cndmask, no divergence)
    const bool aAct = (tA <= thiA);
    const bool bAct = (tB <= thiB);
    nA = aAct ? (__logf(sA) + rA0) : nA;
    nB = bAct ? (__logf(sB) + rB0) : nB;
    SA += aAct ? mA : 0.f;
    SB += bAct ? mB : 0.f;
    rA0 = rA1; rA1 = rA2; rA2 = rA3; rA3 = rnA;
    rB0 = rB1; rB1 = rB2; rB2 = rB3; rB3 = rnB;
    if (i == 30) {  // t == cL-1 for both chains: discard warm-up scale
      if (cA > 0) SA = -wave_lse(nA);
      if (Bact) SB = -wave_lse(nB);
    }
  }

  float ev = endv[lane];
  if (bget(fen, lane, i32)) ev = IMPOSSIBLE;
  const bool hasEndA = (len <= LA + CHUNK);  // only cA=15 & len==2048
  float zcA = hasEndA ? wave_lse(nA + ev) : wave_lse(nA);
  float res = SA + zcA;
  if (Bact) {
    const bool hasEndB = (len <= LB + CHUNK);
    float zcB = hasEndB ? wave_lse(nB + ev) : wave_lse(nB);
    res += SB + zcB;
  }
  if (lane == 0) atomicAdd(out + b, res);
}

// ---------------- z0: gold-path score, wave-per-row ballot version ----------
// (unchanged: ~12 us under the overhead model)
__global__ __launch_bounds__(256) void crf_z0(
    const float* __restrict__ em, const void* __restrict__ mask,
    const void* __restrict__ target, const float* __restrict__ trans,
    const float* __restrict__ startv, const float* __restrict__ endv,
    const void* __restrict__ ftr, const void* __restrict__ fst,
    const void* __restrict__ fen, float* __restrict__ out) {
  const int tid = threadIdx.x;
  const int lane = tid & 63;
  const int w = tid >> 6;
  const int b = blockIdx.x >> 4;
  const int q = blockIdx.x & 15;
  const bool i32 = bools_are_i32(mask);

  __shared__ int lred[4];
  __shared__ int tags[257];
  __shared__ float fred4[4];

  // ---- block-wide len[b] = sum(mask[b,:]) ----
  int ls = 0;
  if (i32) {
    const uint4* mv = (const uint4*)((const int*)mask + (size_t)b * TT);
#pragma unroll
    for (int k = 0; k < 4; ++k) {   // 1024 uint4 = 4096 ints
      uint4 u = mv[k * 256 + tid];
      ls += (int)(u.x + u.y + u.z + u.w);
    }
  } else {
    uint4 u = ((const uint4*)((const unsigned char*)mask + (size_t)b * TT))[tid];
    ls = bytesum4(u.x) + bytesum4(u.y) + bytesum4(u.z) + bytesum4(u.w);
  }
  ls = wave_sum_i32(ls);
  if (lane == 0) lred[w] = ls;

  // ---- tag extraction: wave w scans rows t0 + w*64 .. +63 ----
  const int t0 = q * 256;
  int mytag = 0;
  const size_t rb = ((size_t)b * TT + t0 + (size_t)w * 64) * NN + lane;
  if (i32) {
    const int* tg = (const int*)target + rb;
    for (int k = 0; k < 8; ++k) {
      int v[8];
#pragma unroll
      for (int j = 0; j < 8; ++j) v[j] = tg[(size_t)(k * 8 + j) * NN];
#pragma unroll
      for (int j = 0; j < 8; ++j) {
        unsigned long long bm = __ballot(v[j] != 0);
        int tv = __ffsll(bm) - 1;
        if (lane == k * 8 + j) mytag = tv;
      }
    }
  } else {
    const unsigned char* tg = (const unsigned char*)target + rb;
    for (int k = 0; k < 8; ++k) {
      int v[8];
#pragma unroll
      for (int j = 0; j < 8; ++j) v[j] = (int)tg[(size_t)(k * 8 + j) * NN];
#pragma unroll
      for (int j = 0; j < 8; ++j) {
        unsigned long long bm = __ballot(v[j] != 0);
        int tv = __ffsll(bm) - 1;
        if (lane == k * 8 + j) mytag = tv;
      }
    }
  }
  tags[tid + 1] = mytag;
  if (w == 0) {  // boundary row t0-1 for the block's first transition
    int rp = (t0 == 0) ? 0 : t0 - 1;
    int vv = i32 ? ((const int*)target)[((size_t)b * TT + rp) * NN + lane]
                 : (int)((const unsigned char*)
                       target)[((size_t)b * TT + rp) * NN + lane];
    unsigned long long bm = __ballot(vv != 0);
    int tv = __ffsll(bm) - 1;
    if (tid == 0) tags[0] = (t0 == 0) ? 0 : tv;
  }
  __syncthreads();  // publish lred + tags
  const int len = lred[0] + lred[1] + lred[2] + lred[3];

  const int t = t0 + tid;
  float contrib = 0.f;
  if (t < len) {
    int tg = tags[tid + 1];
    float emv = em[((size_t)b * TT + t) * NN + tg];
    if (t == 0) {
      float sv = startv[tg];
      if (bget(fst, tg, i32)) sv = IMPOSSIBLE;
      contrib = sv + emv;
    } else {
      int tp = tags[tid];
      float tv = trans[tp * NN + tg];
      if (bget(ftr, tp * NN + tg, i32)) tv = IMPOSSIBLE;
      contrib = tv + emv;
    }
    if (t == len - 1) {
      float evv = endv[tg];
      if (bget(fen, tg, i32)) evv = IMPOSSIBLE;
      contrib += evv;
    }
  }
  float wsum = wave_sum_f32(contrib);
  if (lane == 0) fred4[w] = wsum;
  __syncthreads();
  if (tid == 0)
    atomicAdd(out + b, -(fred4[0] + fred4[1] + fred4[2] + fred4[3]));
}

extern "C" void kernel_launch(void* const* d_in, const int* in_sizes, int n_in,
                              void* d_out, int out_size, void* d_ws,
                              size_t ws_size, hipStream_t stream) {
  const float* em = (const float*)d_in[0];
  const void* mask = d_in[1];
  const void* target = d_in[2];
  const float* trans = (const float*)d_in[3];
  const float* startv = (const float*)d_in[4];
  const float* endv = (const float*)d_in[5];
  const void* ftr = d_in[6];
  const void* fst = d_in[7];
  const void* fen = d_in[8];
  float* out = (float*)d_out;

  hipMemsetAsync(out, 0, BB * sizeof(float), stream);
  crf_z1<<<dim3(BB * 16), dim3(64), 0, stream>>>(em, mask, trans, startv,
                                                 endv, ftr, fst, fen, out);
  crf_z0<<<dim3(BB * 16), dim3(256), 0, stream>>>(
      em, mask, target, trans, startv, endv, ftr, fst, fen, out);
}

// Round 10
// 228.471 us; speedup vs baseline: 1.2970x; 1.0839x over previous
//
#include <hip/hip_runtime.h>
#include <stdint.h>

#define IMPOSSIBLE -10000.0f
#define TT 4096
#define NN 64
#define BB 64
#define CHUNK 128           // time-steps per chunk (R6-validated: 8 waves/CU)
#define WARM 32             // warm-up steps (Birkhoff contraction ~0.34/step -> ~1e-14)
#define KCH (TT / CHUNK)    // 32 chunks per sequence

typedef _Float16 half2_t __attribute__((ext_vector_type(2)));

__device__ __forceinline__ float fdot2f(half2_t a, half2_t b, float c) {
#if __has_builtin(__builtin_amdgcn_fdot2)
  return __builtin_amdgcn_fdot2(a, b, c, false);
#else
  return c + (float)a[0] * (float)b[0] + (float)a[1] * (float)b[1];
#endif
}

// ---- bool-input dtype shim: harness may pass jnp.bool as int32 or uint8 ----
// mask[0][0..3] are always true (len >= T/2), so first word distinguishes:
//   uint8 layout -> 0x01010101 ; int32 layout -> 0x00000001
__device__ __forceinline__ bool bools_are_i32(const void* mask) {
  return ((const unsigned int*)mask)[0] == 1u;
}
__device__ __forceinline__ int bget(const void* p, int idx, bool i32) {
  return i32 ? ((const int*)p)[idx] : (int)((const unsigned char*)p)[idx];
}

// ---- DPP wave-64 reductions (VALU only) ----
__device__ __forceinline__ float wave_max_f32(float x) {
  int t;
#define STEP(ctrl)                                                            \
  t = __builtin_amdgcn_update_dpp(__float_as_int(x), __float_as_int(x), ctrl, \
                                  0xf, 0xf, false);                           \
  x = fmaxf(x, __int_as_float(t));
  STEP(0x111) STEP(0x112) STEP(0x114) STEP(0x118) STEP(0x142) STEP(0x143)
#undef STEP
  return __int_as_float(__builtin_amdgcn_readlane(__float_as_int(x), 63));
}

__device__ __forceinline__ float wave_sum_f32(float x) {
  int t;
#define STEP(ctrl)                                                         \
  t = __builtin_amdgcn_update_dpp(0, __float_as_int(x), ctrl, 0xf, 0xf,    \
                                  true);                                   \
  x += __int_as_float(t);
  STEP(0x111) STEP(0x112) STEP(0x114) STEP(0x118) STEP(0x142) STEP(0x143)
#undef STEP
  return __int_as_float(__builtin_amdgcn_readlane(__float_as_int(x), 63));
}

__device__ __forceinline__ int wave_sum_i32(int x) {
  int t;
#define STEP(ctrl)                                                      \
  t = __builtin_amdgcn_update_dpp(0, x, ctrl, 0xf, 0xf, true);          \
  x += t;
  STEP(0x111) STEP(0x112) STEP(0x114) STEP(0x118) STEP(0x142) STEP(0x143)
#undef STEP
  return __builtin_amdgcn_readlane(x, 63);
}

__device__ __forceinline__ float wave_lse(float x) {
  float m = wave_max_f32(x);
  float s = wave_sum_f32(__expf(x - m));
  return m + __logf(s);
}

__device__ __forceinline__ int bytesum4(unsigned int u) {
  return (int)((u * 0x01010101u) >> 24);  // bytes are 0/1, sum <= 4
}

// ---------------- z1: chunked forward recurrence with warm-up ----------------
// R6 kernel (best: 89us) with EXACTLY ONE change: the inline
// asm("s_waitcnt lgkmcnt(0)" ::: "memory") is REMOVED.
// Theory (fits R0-R9): the "memory" clobber makes LLVM's waitcnt pass treat
// the asm as may-access-any-memory and drain vmcnt(0) before it -- putting
// the full L3/HBM latency of the em load issued THIS iteration on the serial
// chain, every iteration, in every round since R3 (and __syncthreads did the
// same before that). The prefetch ring has never been live.
// Correctness without the asm: same-wave DS ops execute in-order through the
// LDS pipe (the read issued after the write returns post-write data), and the
// compiler inserts the counted lgkmcnt(N) before the first fdot2 that
// consumes the read results. sched_barrier(0) fences only constrain the
// scheduler (keep write -> read-cluster -> FMA order); they do not force
// counter drains.
__global__ __launch_bounds__(64, 2) void crf_z1(
    const float* __restrict__ em, const void* __restrict__ mask,
    const float* __restrict__ trans, const float* __restrict__ startv,
    const float* __restrict__ endv, const void* __restrict__ ftr,
    const void* __restrict__ fst, const void* __restrict__ fen,
    float* __restrict__ out) {
  const int lane = threadIdx.x;
  const int b = blockIdx.x >> 5;   // KCH == 32
  const int c = blockIdx.x & 31;
  const bool i32 = bools_are_i32(mask);

  // len[b] = sum(mask[b, :])
  int ls = 0;
  if (i32) {
    const uint4* mv = (const uint4*)((const int*)mask + (size_t)b * TT);
#pragma unroll
    for (int k = 0; k < 16; ++k) {               // 1024 uint4 = 4096 ints
      uint4 w = mv[k * 64 + lane];
      ls += (int)(w.x + w.y + w.z + w.w);
    }
  } else {
    const uint4* mv = (const uint4*)((const unsigned char*)mask + (size_t)b * TT);
#pragma unroll
    for (int k = 0; k < 4; ++k) {                // 256 uint4 = 4096 bytes
      uint4 w = mv[k * 64 + lane];
      ls += bytesum4(w.x) + bytesum4(w.y) + bytesum4(w.z) + bytesum4(w.w);
    }
  }
  const int len = wave_sum_i32(ls);

  const int cL = c * CHUNK;
  if (cL >= len) return;  // chunk entirely beyond sequence end (wave-uniform)
  const int e_c = min(cL + CHUNK - 1, len - 1);
  const bool has_end = (len <= cL + CHUNK);  // len-1 inside this chunk

  // ET[i][j] = exp(masked trans[i][j]); lane j holds column j as 32 f16 pairs
  half2_t et2[32];
#pragma unroll
  for (int i2 = 0; i2 < 32; ++i2) {
    int i0 = 2 * i2, i1 = 2 * i2 + 1;
    float t0 = trans[i0 * NN + lane];
    float t1 = trans[i1 * NN + lane];
    if (bget(ftr, i0 * NN + lane, i32)) t0 = IMPOSSIBLE;
    if (bget(ftr, i1 * NN + lane, i32)) t1 = IMPOSSIBLE;
    half2_t h;
    h[0] = (_Float16)__expf(t0);
    h[1] = (_Float16)__expf(t1);
    et2[i2] = h;
  }

  const float* emb = em + (size_t)b * TT * NN + lane;
  float n, S = 0.f;
  int tb;
  if (c == 0) {
    float sv = startv[lane];
    if (bget(fst, lane, i32)) sv = IMPOSSIBLE;
    n = sv + emb[0];
    tb = 1;
  } else {
    int tw = cL - WARM;
    n = emb[(size_t)tw * NN];  // arbitrary init; warm-up forgets it
    tb = tw + 1;
  }

  __shared__ __align__(16) _Float16 pbuf[2][64];

  // depth-6 em prefetch ring: one load/iter, consumed 6 iters later; with the
  // asm drain gone, these loads finally stay in flight across iterations.
  float r0 = emb[(size_t)tb * NN];
  float r1 = emb[(size_t)min(tb + 1, TT - 1) * NN];
  float r2 = emb[(size_t)min(tb + 2, TT - 1) * NN];
  float r3 = emb[(size_t)min(tb + 3, TT - 1) * NN];
  float r4 = emb[(size_t)min(tb + 4, TT - 1) * NN];
  float r5 = emb[(size_t)min(tb + 5, TT - 1) * NN];

  for (int t = tb; t <= e_c; ++t) {
    float rn = emb[(size_t)min(t + 6, TT - 1) * NN];  // prefetch t+6
    float m = wave_max_f32(n);
    float p = __expf(n - m);
    const int par = t & 1;
    pbuf[par][lane] = (_Float16)p;
    // NO explicit waitcnt: same-wave DS ops are in-order (read-after-write to
    // pbuf returns the new data); the compiler inserts the counted lgkmcnt
    // before the first consuming fdot2. No vmcnt drain anywhere in the loop.
    __builtin_amdgcn_sched_barrier(0);
    const uint4* pv = (const uint4*)pbuf[par];
    uint4 qa[8];
#pragma unroll
    for (int k = 0; k < 8; ++k) qa[k] = pv[k];  // 8x ds_read_b128, one cluster
    __builtin_amdgcn_sched_barrier(0);          // all reads issued before FMAs
    float s0 = 0.f, s1 = 0.f, s2 = 0.f, s3 = 0.f;
#pragma unroll
    for (int k = 0; k < 8; ++k) {
      s0 = fdot2f(__builtin_bit_cast(half2_t, qa[k].x), et2[4 * k + 0], s0);
      s1 = fdot2f(__builtin_bit_cast(half2_t, qa[k].y), et2[4 * k + 1], s1);
      s2 = fdot2f(__builtin_bit_cast(half2_t, qa[k].z), et2[4 * k + 2], s2);
      s3 = fdot2f(__builtin_bit_cast(half2_t, qa[k].w), et2[4 * k + 3], s3);
    }
    float s = (s0 + s1) + (s2 + s3);
    n = __logf(s) + r0;
    S += m;
    r0 = r1; r1 = r2; r2 = r3; r3 = r4; r4 = r5; r5 = rn;
    if (c > 0 && t == cL - 1) S = -wave_lse(n);  // discard warm-up scale
  }

  float ev = endv[lane];
  if (bget(fen, lane, i32)) ev = IMPOSSIBLE;
  float zc = has_end ? wave_lse(n + ev) : wave_lse(n);
  if (lane == 0) atomicAdd(out + b, S + zc);
}

// ---------------- z0: gold-path score, wave-per-row ballot version ----------
// (unchanged: ~12 us under the overhead model)
__global__ __launch_bounds__(256) void crf_z0(
    const float* __restrict__ em, const void* __restrict__ mask,
    const void* __restrict__ target, const float* __restrict__ trans,
    const float* __restrict__ startv, const float* __restrict__ endv,
    const void* __restrict__ ftr, const void* __restrict__ fst,
    const void* __restrict__ fen, float* __restrict__ out) {
  const int tid = threadIdx.x;
  const int lane = tid & 63;
  const int w = tid >> 6;
  const int b = blockIdx.x >> 4;
  const int q = blockIdx.x & 15;
  const bool i32 = bools_are_i32(mask);

  __shared__ int lred[4];
  __shared__ int tags[257];
  __shared__ float fred4[4];

  // ---- block-wide len[b] = sum(mask[b,:]) ----
  int ls = 0;
  if (i32) {
    const uint4* mv = (const uint4*)((const int*)mask + (size_t)b * TT);
#pragma unroll
    for (int k = 0; k < 4; ++k) {   // 1024 uint4 = 4096 ints
      uint4 u = mv[k * 256 + tid];
      ls += (int)(u.x + u.y + u.z + u.w);
    }
  } else {
    uint4 u = ((const uint4*)((const unsigned char*)mask + (size_t)b * TT))[tid];
    ls = bytesum4(u.x) + bytesum4(u.y) + bytesum4(u.z) + bytesum4(u.w);
  }
  ls = wave_sum_i32(ls);
  if (lane == 0) lred[w] = ls;

  // ---- tag extraction: wave w scans rows t0 + w*64 .. +63 ----
  const int t0 = q * 256;
  int mytag = 0;
  const size_t rb = ((size_t)b * TT + t0 + (size_t)w * 64) * NN + lane;
  if (i32) {
    const int* tg = (const int*)target + rb;
    for (int k = 0; k < 8; ++k) {
      int v[8];
#pragma unroll
      for (int j = 0; j < 8; ++j) v[j] = tg[(size_t)(k * 8 + j) * NN];
#pragma unroll
      for (int j = 0; j < 8; ++j) {
        unsigned long long bm = __ballot(v[j] != 0);
        int tv = __ffsll(bm) - 1;
        if (lane == k * 8 + j) mytag = tv;
      }
    }
  } else {
    const unsigned char* tg = (const unsigned char*)target + rb;
    for (int k = 0; k < 8; ++k) {
      int v[8];
#pragma unroll
      for (int j = 0; j < 8; ++j) v[j] = (int)tg[(size_t)(k * 8 + j) * NN];
#pragma unroll
      for (int j = 0; j < 8; ++j) {
        unsigned long long bm = __ballot(v[j] != 0);
        int tv = __ffsll(bm) - 1;
        if (lane == k * 8 + j) mytag = tv;
      }
    }
  }
  tags[tid + 1] = mytag;
  if (w == 0) {  // boundary row t0-1 for the block's first transition
    int rp = (t0 == 0) ? 0 : t0 - 1;
    int vv = i32 ? ((const int*)target)[((size_t)b * TT + rp) * NN + lane]
                 : (int)((const unsigned char*)
                       target)[((size_t)b * TT + rp) * NN + lane];
    unsigned long long bm = __ballot(vv != 0);
    int tv = __ffsll(bm) - 1;
    if (tid == 0) tags[0] = (t0 == 0) ? 0 : tv;
  }
  __syncthreads();  // publish lred + tags
  const int len = lred[0] + lred[1] + lred[2] + lred[3];

  const int t = t0 + tid;
  float contrib = 0.f;
  if (t < len) {
    int tg = tags[tid + 1];
    float emv = em[((size_t)b * TT + t) * NN + tg];
    if (t == 0) {
      float sv = startv[tg];
      if (bget(fst, tg, i32)) sv = IMPOSSIBLE;
      contrib = sv + emv;
    } else {
      int tp = tags[tid];
      float tv = trans[tp * NN + tg];
      if (bget(ftr, tp * NN + tg, i32)) tv = IMPOSSIBLE;
      contrib = tv + emv;
    }
    if (t == len - 1) {
      float evv = endv[tg];
      if (bget(fen, tg, i32)) evv = IMPOSSIBLE;
      contrib += evv;
    }
  }
  float wsum = wave_sum_f32(contrib);
  if (lane == 0) fred4[w] = wsum;
  __syncthreads();
  if (tid == 0)
    atomicAdd(out + b, -(fred4[0] + fred4[1] + fred4[2] + fred4[3]));
}

extern "C" void kernel_launch(void* const* d_in, const int* in_sizes, int n_in,
                              void* d_out, int out_size, void* d_ws,
                              size_t ws_size, hipStream_t stream) {
  const float* em = (const float*)d_in[0];
  const void* mask = d_in[1];
  const void* target = d_in[2];
  const float* trans = (const float*)d_in[3];
  const float* startv = (const float*)d_in[4];
  const float* endv = (const float*)d_in[5];
  const void* ftr = d_in[6];
  const void* fst = d_in[7];
  const void* fen = d_in[8];
  float* out = (float*)d_out;

  hipMemsetAsync(out, 0, BB * sizeof(float), stream);
  crf_z1<<<dim3(BB * KCH), dim3(64), 0, stream>>>(em, mask, trans, startv,
                                                  endv, ftr, fst, fen, out);
  crf_z0<<<dim3(BB * 16), dim3(256), 0, stream>>>(
      em, mask, target, trans, startv, endv, ftr, fst, fen, out);
}

// Round 11
// 227.756 us; speedup vs baseline: 1.3011x; 1.0031x over previous
//
#include <hip/hip_runtime.h>
#include <stdint.h>

#define IMPOSSIBLE -10000.0f
#define TT 4096
#define NN 64
#define BB 64
#define CHUNK 128           // time-steps per chunk (R6-validated geometry: 8 waves/CU)
#define WARM 32             // warm-up steps (Birkhoff contraction ~0.34/step -> ~1e-14)
#define KCH (TT / CHUNK)    // 32 chunks per sequence
#define LN_DAMP 3.46573590f // 5*ln2: per-step damp 2^-5 keeps p in f32 range

typedef float f32x2 __attribute__((ext_vector_type(2)));

// ---- bool-input dtype shim: harness may pass jnp.bool as int32 or uint8 ----
// mask[0][0..3] are always true (len >= T/2), so first word distinguishes:
//   uint8 layout -> 0x01010101 ; int32 layout -> 0x00000001
__device__ __forceinline__ bool bools_are_i32(const void* mask) {
  return ((const unsigned int*)mask)[0] == 1u;
}
__device__ __forceinline__ int bget(const void* p, int idx, bool i32) {
  return i32 ? ((const int*)p)[idx] : (int)((const unsigned char*)p)[idx];
}

// ---- DPP wave-64 reductions (VALU only) ----
__device__ __forceinline__ float wave_max_f32(float x) {
  int t;
#define STEP(ctrl)                                                            \
  t = __builtin_amdgcn_update_dpp(__float_as_int(x), __float_as_int(x), ctrl, \
                                  0xf, 0xf, false);                           \
  x = fmaxf(x, __int_as_float(t));
  STEP(0x111) STEP(0x112) STEP(0x114) STEP(0x118) STEP(0x142) STEP(0x143)
#undef STEP
  return __int_as_float(__builtin_amdgcn_readlane(__float_as_int(x), 63));
}

__device__ __forceinline__ float wave_sum_f32(float x) {
  int t;
#define STEP(ctrl)                                                         \
  t = __builtin_amdgcn_update_dpp(0, __float_as_int(x), ctrl, 0xf, 0xf,    \
                                  true);                                   \
  x += __int_as_float(t);
  STEP(0x111) STEP(0x112) STEP(0x114) STEP(0x118) STEP(0x142) STEP(0x143)
#undef STEP
  return __int_as_float(__builtin_amdgcn_readlane(__float_as_int(x), 63));
}

__device__ __forceinline__ int wave_sum_i32(int x) {
  int t;
#define STEP(ctrl)                                                      \
  t = __builtin_amdgcn_update_dpp(0, x, ctrl, 0xf, 0xf, true);          \
  x += t;
  STEP(0x111) STEP(0x112) STEP(0x114) STEP(0x118) STEP(0x142) STEP(0x143)
#undef STEP
  return __builtin_amdgcn_readlane(x, 63);
}

__device__ __forceinline__ int bytesum4(unsigned int u) {
  return (int)((u * 0x01010101u) >> 24);  // bytes are 0/1, sum <= 4
}

// ---------------- z1: linear-space recurrence at the winning geometry -------
// Numerics = R3 (harness-verified, absmax 0.0): p linear f32 + scale S;
//   p'_j = (sum_i p_i ET[i][j]) * exp(em_j - 5ln2); S += 5ln2;
//   exact wave-max renorm every 8th step; warm-up discard = sum-normalize.
// Geometry/scheduling = R6/R10 (best measured): CHUNK=128 (2 waves/SIMD),
//   NO waitcnt asm (R10 proved same-wave DS in-order is correct), clustered
//   ds_read_b128, depth-6 em prefetch ring (vmcnt never drained).
// Why: R0-R10 pin the per-step cost at ~670cy/SIMD-slot in every log-space
// variant. The only per-step ops priced wrong in the issue model are the
// quarter-rate transcendentals (exp+log) and the 6-deep DPP max -- log-space
// puts 2 trans + 1 wave-reduce on EVERY step's chain. Linear space moves the
// exp off-chain (depends only on the em ring), drops the log entirely, and
// amortizes the wave-reduce 8x. Range proof in R3 header (f32 spans e^+-87;
// drift bounded +-10 nats/step with 2^-5 damp, renorm every 8).
__global__ __launch_bounds__(64, 2) void crf_z1(
    const float* __restrict__ em, const void* __restrict__ mask,
    const float* __restrict__ trans, const float* __restrict__ startv,
    const float* __restrict__ endv, const void* __restrict__ ftr,
    const void* __restrict__ fst, const void* __restrict__ fen,
    float* __restrict__ out) {
  const int lane = threadIdx.x;
  const int b = blockIdx.x >> 5;   // KCH == 32
  const int c = blockIdx.x & 31;
  const bool i32 = bools_are_i32(mask);

  // len[b] = sum(mask[b, :])
  int ls = 0;
  if (i32) {
    const uint4* mv = (const uint4*)((const int*)mask + (size_t)b * TT);
#pragma unroll
    for (int k = 0; k < 16; ++k) {               // 1024 uint4 = 4096 ints
      uint4 w = mv[k * 64 + lane];
      ls += (int)(w.x + w.y + w.z + w.w);
    }
  } else {
    const uint4* mv = (const uint4*)((const unsigned char*)mask + (size_t)b * TT);
#pragma unroll
    for (int k = 0; k < 4; ++k) {                // 256 uint4 = 4096 bytes
      uint4 w = mv[k * 64 + lane];
      ls += bytesum4(w.x) + bytesum4(w.y) + bytesum4(w.z) + bytesum4(w.w);
    }
  }
  const int len = wave_sum_i32(ls);

  const int cL = c * CHUNK;
  if (cL >= len) return;  // chunk entirely beyond sequence end (wave-uniform)
  const int e_c = min(cL + CHUNK - 1, len - 1);
  const bool has_end = (len <= cL + CHUNK);  // len-1 inside this chunk

  // ET in f32: lane j holds column j; etf[m] = (ET[2m][j], ET[2m+1][j]).
  f32x2 etf[32];
#pragma unroll
  for (int m = 0; m < 32; ++m) {
    int i0 = 2 * m, i1 = 2 * m + 1;
    float t0 = trans[i0 * NN + lane];
    float t1 = trans[i1 * NN + lane];
    if (bget(ftr, i0 * NN + lane, i32)) t0 = IMPOSSIBLE;
    if (bget(ftr, i1 * NN + lane, i32)) t1 = IMPOSSIBLE;
    f32x2 h;
    h[0] = __expf(t0);   // exp(-10000) == 0: forbidden transitions drop out
    h[1] = __expf(t1);
    etf[m] = h;
  }

  const float* emb = em + (size_t)b * TT * NN + lane;
  float p, S;
  int tb;
  if (c == 0) {
    float sv = startv[lane];
    if (bget(fst, lane, i32)) sv = IMPOSSIBLE;
    float a0 = sv + emb[0];
    float m0 = wave_max_f32(a0);
    p = __expf(a0 - m0);   // forbidden start -> exp underflows to 0: ok
    S = m0;
    tb = 1;
  } else {
    p = 1.0f;              // arbitrary positive init; warm-up forgets it
    S = 0.f;               // discarded at t == cL-1 anyway
    tb = cL - WARM + 1;    // 31 warm-up transitions before cL
  }

  __shared__ __align__(16) float pbuf[2][64];

  // depth-6 em prefetch ring: one load/iter, consumed 6 iters later; no
  // barrier, no waitcnt asm anywhere in the loop -> vmcnt stays counted.
  float r0 = emb[(size_t)tb * NN];
  float r1 = emb[(size_t)min(tb + 1, TT - 1) * NN];
  float r2 = emb[(size_t)min(tb + 2, TT - 1) * NN];
  float r3 = emb[(size_t)min(tb + 3, TT - 1) * NN];
  float r4 = emb[(size_t)min(tb + 4, TT - 1) * NN];
  float r5 = emb[(size_t)min(tb + 5, TT - 1) * NN];

  for (int t = tb; t <= e_c; ++t) {
    float rn = emb[(size_t)min(t + 6, TT - 1) * NN];  // prefetch t+6
    float ex = __expf(r0 - LN_DAMP);  // e^{em_t}*2^-5: OFF the p-chain
    const int par = t & 1;
    pbuf[par][lane] = p;
    // same-wave DS in-order (R10-verified): no explicit waitcnt; compiler
    // inserts the counted lgkmcnt before the first consuming FMA.
    __builtin_amdgcn_sched_barrier(0);
    const float4* pv = (const float4*)pbuf[par];
    float4 qa[16];
#pragma unroll
    for (int k = 0; k < 16; ++k) qa[k] = pv[k];  // 16x ds_read_b128 broadcast
    __builtin_amdgcn_sched_barrier(0);           // all reads before FMAs
    f32x2 a0 = {0.f, 0.f}, a1 = {0.f, 0.f}, a2 = {0.f, 0.f}, a3 = {0.f, 0.f};
    f32x2 a4 = {0.f, 0.f}, a5 = {0.f, 0.f}, a6 = {0.f, 0.f}, a7 = {0.f, 0.f};
#pragma unroll
    for (int k = 0; k < 8; ++k) {  // 8 accumulators, depth 4 each
      float4 qlo = qa[2 * k], qhi = qa[2 * k + 1];
      f32x2 u0, u1, u2, u3;
      u0[0] = qlo.x; u0[1] = qlo.y;
      u1[0] = qlo.z; u1[1] = qlo.w;
      u2[0] = qhi.x; u2[1] = qhi.y;
      u3[0] = qhi.z; u3[1] = qhi.w;
      switch (k & 7) {  // static round-robin: 8 independent chains
        case 0: a0 = __builtin_elementwise_fma(u0, etf[4*k+0], a0);
                a1 = __builtin_elementwise_fma(u1, etf[4*k+1], a1);
                a2 = __builtin_elementwise_fma(u2, etf[4*k+2], a2);
                a3 = __builtin_elementwise_fma(u3, etf[4*k+3], a3); break;
        case 1: a4 = __builtin_elementwise_fma(u0, etf[4*k+0], a4);
                a5 = __builtin_elementwise_fma(u1, etf[4*k+1], a5);
                a6 = __builtin_elementwise_fma(u2, etf[4*k+2], a6);
                a7 = __builtin_elementwise_fma(u3, etf[4*k+3], a7); break;
        case 2: a0 = __builtin_elementwise_fma(u0, etf[4*k+0], a0);
                a1 = __builtin_elementwise_fma(u1, etf[4*k+1], a1);
                a2 = __builtin_elementwise_fma(u2, etf[4*k+2], a2);
                a3 = __builtin_elementwise_fma(u3, etf[4*k+3], a3); break;
        case 3: a4 = __builtin_elementwise_fma(u0, etf[4*k+0], a4);
                a5 = __builtin_elementwise_fma(u1, etf[4*k+1], a5);
                a6 = __builtin_elementwise_fma(u2, etf[4*k+2], a6);
                a7 = __builtin_elementwise_fma(u3, etf[4*k+3], a7); break;
        case 4: a0 = __builtin_elementwise_fma(u0, etf[4*k+0], a0);
                a1 = __builtin_elementwise_fma(u1, etf[4*k+1], a1);
                a2 = __builtin_elementwise_fma(u2, etf[4*k+2], a2);
                a3 = __builtin_elementwise_fma(u3, etf[4*k+3], a3); break;
        case 5: a4 = __builtin_elementwise_fma(u0, etf[4*k+0], a4);
                a5 = __builtin_elementwise_fma(u1, etf[4*k+1], a5);
                a6 = __builtin_elementwise_fma(u2, etf[4*k+2], a6);
                a7 = __builtin_elementwise_fma(u3, etf[4*k+3], a7); break;
        case 6: a0 = __builtin_elementwise_fma(u0, etf[4*k+0], a0);
                a1 = __builtin_elementwise_fma(u1, etf[4*k+1], a1);
                a2 = __builtin_elementwise_fma(u2, etf[4*k+2], a2);
                a3 = __builtin_elementwise_fma(u3, etf[4*k+3], a3); break;
        default: a4 = __builtin_elementwise_fma(u0, etf[4*k+0], a4);
                 a5 = __builtin_elementwise_fma(u1, etf[4*k+1], a5);
                 a6 = __builtin_elementwise_fma(u2, etf[4*k+2], a6);
                 a7 = __builtin_elementwise_fma(u3, etf[4*k+3], a7); break;
      }
    }
    f32x2 s2 = ((a0 + a1) + (a2 + a3)) + ((a4 + a5) + (a6 + a7));
    float s = s2[0] + s2[1];
    p = s * ex;          // chain: reads -> fma tree -> mul. No trans, no max.
    S += LN_DAMP;
    r0 = r1; r1 = r2; r2 = r3; r3 = r4; r4 = r5; r5 = rn;
    if (c > 0 && t == cL - 1) {
      // warm-up discard: normalize to sum 1, reset scale (telescoping ref pt)
      float ssum = wave_sum_f32(p);
      p *= 1.0f / ssum;
      S = 0.f;
    } else if (((t - tb) & 7) == 7) {
      float r = wave_max_f32(p);  // every 8th step only: off the hot chain
      p *= 1.0f / r;
      S += __logf(r);
    }
  }

  float w_ = p;
  if (has_end) {
    float ev = endv[lane];
    if (bget(fen, lane, i32)) ev = IMPOSSIBLE;
    w_ = p * __expf(ev);  // e^{-10000} == 0: forbidden end states drop out
  }
  float zc = S + __logf(wave_sum_f32(w_));
  if (lane == 0) atomicAdd(out + b, zc);
}

// ---------------- z0: gold-path score, wave-per-row ballot version ----------
// (unchanged: ~12 us under the overhead model)
__global__ __launch_bounds__(256) void crf_z0(
    const float* __restrict__ em, const void* __restrict__ mask,
    const void* __restrict__ target, const float* __restrict__ trans,
    const float* __restrict__ startv, const float* __restrict__ endv,
    const void* __restrict__ ftr, const void* __restrict__ fst,
    const void* __restrict__ fen, float* __restrict__ out) {
  const int tid = threadIdx.x;
  const int lane = tid & 63;
  const int w = tid >> 6;
  const int b = blockIdx.x >> 4;
  const int q = blockIdx.x & 15;
  const bool i32 = bools_are_i32(mask);

  __shared__ int lred[4];
  __shared__ int tags[257];
  __shared__ float fred4[4];

  // ---- block-wide len[b] = sum(mask[b,:]) ----
  int ls = 0;
  if (i32) {
    const uint4* mv = (const uint4*)((const int*)mask + (size_t)b * TT);
#pragma unroll
    for (int k = 0; k < 4; ++k) {   // 1024 uint4 = 4096 ints
      uint4 u = mv[k * 256 + tid];
      ls += (int)(u.x + u.y + u.z + u.w);
    }
  } else {
    uint4 u = ((const uint4*)((const unsigned char*)mask + (size_t)b * TT))[tid];
    ls = bytesum4(u.x) + bytesum4(u.y) + bytesum4(u.z) + bytesum4(u.w);
  }
  ls = wave_sum_i32(ls);
  if (lane == 0) lred[w] = ls;

  // ---- tag extraction: wave w scans rows t0 + w*64 .. +63 ----
  const int t0 = q * 256;
  int mytag = 0;
  const size_t rb = ((size_t)b * TT + t0 + (size_t)w * 64) * NN + lane;
  if (i32) {
    const int* tg = (const int*)target + rb;
    for (int k = 0; k < 8; ++k) {
      int v[8];
#pragma unroll
      for (int j = 0; j < 8; ++j) v[j] = tg[(size_t)(k * 8 + j) * NN];
#pragma unroll
      for (int j = 0; j < 8; ++j) {
        unsigned long long bm = __ballot(v[j] != 0);
        int tv = __ffsll(bm) - 1;
        if (lane == k * 8 + j) mytag = tv;
      }
    }
  } else {
    const unsigned char* tg = (const unsigned char*)target + rb;
    for (int k = 0; k < 8; ++k) {
      int v[8];
#pragma unroll
      for (int j = 0; j < 8; ++j) v[j] = (int)tg[(size_t)(k * 8 + j) * NN];
#pragma unroll
      for (int j = 0; j < 8; ++j) {
        unsigned long long bm = __ballot(v[j] != 0);
        int tv = __ffsll(bm) - 1;
        if (lane == k * 8 + j) mytag = tv;
      }
    }
  }
  tags[tid + 1] = mytag;
  if (w == 0) {  // boundary row t0-1 for the block's first transition
    int rp = (t0 == 0) ? 0 : t0 - 1;
    int vv = i32 ? ((const int*)target)[((size_t)b * TT + rp) * NN + lane]
                 : (int)((const unsigned char*)
                       target)[((size_t)b * TT + rp) * NN + lane];
    unsigned long long bm = __ballot(vv != 0);
    int tv = __ffsll(bm) - 1;
    if (tid == 0) tags[0] = (t0 == 0) ? 0 : tv;
  }
  __syncthreads();  // publish lred + tags
  const int len = lred[0] + lred[1] + lred[2] + lred[3];

  const int t = t0 + tid;
  float contrib = 0.f;
  if (t < len) {
    int tg = tags[tid + 1];
    float emv = em[((size_t)b * TT + t) * NN + tg];
    if (t == 0) {
      float sv = startv[tg];
      if (bget(fst, tg, i32)) sv = IMPOSSIBLE;
      contrib = sv + emv;
    } else {
      int tp = tags[tid];
      float tv = trans[tp * NN + tg];
      if (bget(ftr, tp * NN + tg, i32)) tv = IMPOSSIBLE;
      contrib = tv + emv;
    }
    if (t == len - 1) {
      float evv = endv[tg];
      if (bget(fen, tg, i32)) evv = IMPOSSIBLE;
      contrib += evv;
    }
  }
  float wsum = wave_sum_f32(contrib);
  if (lane == 0) fred4[w] = wsum;
  __syncthreads();
  if (tid == 0)
    atomicAdd(out + b, -(fred4[0] + fred4[1] + fred4[2] + fred4[3]));
}

extern "C" void kernel_launch(void* const* d_in, const int* in_sizes, int n_in,
                              void* d_out, int out_size, void* d_ws,
                              size_t ws_size, hipStream_t stream) {
  const float* em = (const float*)d_in[0];
  const void* mask = d_in[1];
  const void* target = d_in[2];
  const float* trans = (const float*)d_in[3];
  const float* startv = (const float*)d_in[4];
  const float* endv = (const float*)d_in[5];
  const void* ftr = d_in[6];
  const void* fst = d_in[7];
  const void* fen = d_in[8];
  float* out = (float*)d_out;

  hipMemsetAsync(out, 0, BB * sizeof(float), stream);
  crf_z1<<<dim3(BB * KCH), dim3(64), 0, stream>>>(em, mask, trans, startv,
                                                  endv, ftr, fst, fen, out);
  crf_z0<<<dim3(BB * 16), dim3(256), 0, stream>>>(
      em, mask, target, trans, startv, endv, ftr, fst, fen, out);
}

// Round 12
// 223.565 us; speedup vs baseline: 1.3255x; 1.0187x over previous
//
#include <hip/hip_runtime.h>
#include <stdint.h>

#define IMPOSSIBLE -10000.0f
#define TT 4096
#define NN 64
#define BB 64
#define CHUNK 128           // time-steps per chunk (R6-validated geometry: 8 waves/CU)
#define WARM 16             // R12: 32->16. Contraction <=0.38/step -> 0.38^15 ~ 5e-7
                            // nats/boundary, two orders below the f16-ET noise that
                            // already passed. Cuts steps/wave 159->143 (-10%).
#define KCH (TT / CHUNK)    // 32 chunks per sequence
#define LN_DAMP 3.46573590f // 5*ln2: per-step damp 2^-5 keeps p in f32 range

typedef float f32x2 __attribute__((ext_vector_type(2)));

// ---- bool-input dtype shim: harness may pass jnp.bool as int32 or uint8 ----
// mask[0][0..3] are always true (len >= T/2), so first word distinguishes:
//   uint8 layout -> 0x01010101 ; int32 layout -> 0x00000001
__device__ __forceinline__ bool bools_are_i32(const void* mask) {
  return ((const unsigned int*)mask)[0] == 1u;
}
__device__ __forceinline__ int bget(const void* p, int idx, bool i32) {
  return i32 ? ((const int*)p)[idx] : (int)((const unsigned char*)p)[idx];
}

// ---- DPP wave-64 reductions (VALU only) ----
__device__ __forceinline__ float wave_max_f32(float x) {
  int t;
#define STEP(ctrl)                                                            \
  t = __builtin_amdgcn_update_dpp(__float_as_int(x), __float_as_int(x), ctrl, \
                                  0xf, 0xf, false);                           \
  x = fmaxf(x, __int_as_float(t));
  STEP(0x111) STEP(0x112) STEP(0x114) STEP(0x118) STEP(0x142) STEP(0x143)
#undef STEP
  return __int_as_float(__builtin_amdgcn_readlane(__float_as_int(x), 63));
}

__device__ __forceinline__ float wave_sum_f32(float x) {
  int t;
#define STEP(ctrl)                                                         \
  t = __builtin_amdgcn_update_dpp(0, __float_as_int(x), ctrl, 0xf, 0xf,    \
                                  true);                                   \
  x += __int_as_float(t);
  STEP(0x111) STEP(0x112) STEP(0x114) STEP(0x118) STEP(0x142) STEP(0x143)
#undef STEP
  return __int_as_float(__builtin_amdgcn_readlane(__float_as_int(x), 63));
}

__device__ __forceinline__ int wave_sum_i32(int x) {
  int t;
#define STEP(ctrl)                                                      \
  t = __builtin_amdgcn_update_dpp(0, x, ctrl, 0xf, 0xf, true);          \
  x += t;
  STEP(0x111) STEP(0x112) STEP(0x114) STEP(0x118) STEP(0x142) STEP(0x143)
#undef STEP
  return __builtin_amdgcn_readlane(x, 63);
}

__device__ __forceinline__ int bytesum4(unsigned int u) {
  return (int)((u * 0x01010101u) >> 24);  // bytes are 0/1, sum <= 4
}

// ---------------- z1: linear-space recurrence at the winning geometry -------
// Body = R11 (harness-verified, absmax 0.0): p linear f32 + scale S;
//   p'_j = (sum_i p_i ET[i][j]) * exp(em_j - 5ln2); S += 5ln2;
//   exact wave-max renorm every 8th step; warm-up discard = sum-normalize.
// R12 change: WARM 32 -> 16 only.
// Measured law (R0-R11): z1 = wave-steps/SIMD x c, c ~ 612-670 cy, body-
// invariant (log vs linear, f16 vs f32, DS vs readlane all equal) -- the
// remaining lever is the step count itself, i.e. the warm-up fraction.
__global__ __launch_bounds__(64, 2) void crf_z1(
    const float* __restrict__ em, const void* __restrict__ mask,
    const float* __restrict__ trans, const float* __restrict__ startv,
    const float* __restrict__ endv, const void* __restrict__ ftr,
    const void* __restrict__ fst, const void* __restrict__ fen,
    float* __restrict__ out) {
  const int lane = threadIdx.x;
  const int b = blockIdx.x >> 5;   // KCH == 32
  const int c = blockIdx.x & 31;
  const bool i32 = bools_are_i32(mask);

  // len[b] = sum(mask[b, :])
  int ls = 0;
  if (i32) {
    const uint4* mv = (const uint4*)((const int*)mask + (size_t)b * TT);
#pragma unroll
    for (int k = 0; k < 16; ++k) {               // 1024 uint4 = 4096 ints
      uint4 w = mv[k * 64 + lane];
      ls += (int)(w.x + w.y + w.z + w.w);
    }
  } else {
    const uint4* mv = (const uint4*)((const unsigned char*)mask + (size_t)b * TT);
#pragma unroll
    for (int k = 0; k < 4; ++k) {                // 256 uint4 = 4096 bytes
      uint4 w = mv[k * 64 + lane];
      ls += bytesum4(w.x) + bytesum4(w.y) + bytesum4(w.z) + bytesum4(w.w);
    }
  }
  const int len = wave_sum_i32(ls);

  const int cL = c * CHUNK;
  if (cL >= len) return;  // chunk entirely beyond sequence end (wave-uniform)
  const int e_c = min(cL + CHUNK - 1, len - 1);
  const bool has_end = (len <= cL + CHUNK);  // len-1 inside this chunk

  // ET in f32: lane j holds column j; etf[m] = (ET[2m][j], ET[2m+1][j]).
  f32x2 etf[32];
#pragma unroll
  for (int m = 0; m < 32; ++m) {
    int i0 = 2 * m, i1 = 2 * m + 1;
    float t0 = trans[i0 * NN + lane];
    float t1 = trans[i1 * NN + lane];
    if (bget(ftr, i0 * NN + lane, i32)) t0 = IMPOSSIBLE;
    if (bget(ftr, i1 * NN + lane, i32)) t1 = IMPOSSIBLE;
    f32x2 h;
    h[0] = __expf(t0);   // exp(-10000) == 0: forbidden transitions drop out
    h[1] = __expf(t1);
    etf[m] = h;
  }

  const float* emb = em + (size_t)b * TT * NN + lane;
  float p, S;
  int tb;
  if (c == 0) {
    float sv = startv[lane];
    if (bget(fst, lane, i32)) sv = IMPOSSIBLE;
    float a0 = sv + emb[0];
    float m0 = wave_max_f32(a0);
    p = __expf(a0 - m0);   // forbidden start -> exp underflows to 0: ok
    S = m0;
    tb = 1;
  } else {
    p = 1.0f;              // arbitrary positive init; warm-up forgets it
    S = 0.f;               // discarded at t == cL-1 anyway
    tb = cL - WARM + 1;    // WARM-1 warm-up transitions before cL
  }

  __shared__ __align__(16) float pbuf[2][64];

  // depth-6 em prefetch ring: one load/iter, consumed 6 iters later; no
  // barrier, no waitcnt asm anywhere in the loop -> vmcnt stays counted.
  float r0 = emb[(size_t)tb * NN];
  float r1 = emb[(size_t)min(tb + 1, TT - 1) * NN];
  float r2 = emb[(size_t)min(tb + 2, TT - 1) * NN];
  float r3 = emb[(size_t)min(tb + 3, TT - 1) * NN];
  float r4 = emb[(size_t)min(tb + 4, TT - 1) * NN];
  float r5 = emb[(size_t)min(tb + 5, TT - 1) * NN];

  for (int t = tb; t <= e_c; ++t) {
    float rn = emb[(size_t)min(t + 6, TT - 1) * NN];  // prefetch t+6
    float ex = __expf(r0 - LN_DAMP);  // e^{em_t}*2^-5: OFF the p-chain
    const int par = t & 1;
    pbuf[par][lane] = p;
    // same-wave DS in-order (R10-verified): no explicit waitcnt; compiler
    // inserts the counted lgkmcnt before the first consuming FMA.
    __builtin_amdgcn_sched_barrier(0);
    const float4* pv = (const float4*)pbuf[par];
    float4 qa[16];
#pragma unroll
    for (int k = 0; k < 16; ++k) qa[k] = pv[k];  // 16x ds_read_b128 broadcast
    __builtin_amdgcn_sched_barrier(0);           // all reads before FMAs
    f32x2 a0 = {0.f, 0.f}, a1 = {0.f, 0.f}, a2 = {0.f, 0.f}, a3 = {0.f, 0.f};
    f32x2 a4 = {0.f, 0.f}, a5 = {0.f, 0.f}, a6 = {0.f, 0.f}, a7 = {0.f, 0.f};
#pragma unroll
    for (int k = 0; k < 8; ++k) {  // 8 accumulators, depth 4 each
      float4 qlo = qa[2 * k], qhi = qa[2 * k + 1];
      f32x2 u0, u1, u2, u3;
      u0[0] = qlo.x; u0[1] = qlo.y;
      u1[0] = qlo.z; u1[1] = qlo.w;
      u2[0] = qhi.x; u2[1] = qhi.y;
      u3[0] = qhi.z; u3[1] = qhi.w;
      switch (k & 7) {  // static round-robin: 8 independent chains
        case 0: a0 = __builtin_elementwise_fma(u0, etf[4*k+0], a0);
                a1 = __builtin_elementwise_fma(u1, etf[4*k+1], a1);
                a2 = __builtin_elementwise_fma(u2, etf[4*k+2], a2);
                a3 = __builtin_elementwise_fma(u3, etf[4*k+3], a3); break;
        case 1: a4 = __builtin_elementwise_fma(u0, etf[4*k+0], a4);
                a5 = __builtin_elementwise_fma(u1, etf[4*k+1], a5);
                a6 = __builtin_elementwise_fma(u2, etf[4*k+2], a6);
                a7 = __builtin_elementwise_fma(u3, etf[4*k+3], a7); break;
        case 2: a0 = __builtin_elementwise_fma(u0, etf[4*k+0], a0);
                a1 = __builtin_elementwise_fma(u1, etf[4*k+1], a1);
                a2 = __builtin_elementwise_fma(u2, etf[4*k+2], a2);
                a3 = __builtin_elementwise_fma(u3, etf[4*k+3], a3); break;
        case 3: a4 = __builtin_elementwise_fma(u0, etf[4*k+0], a4);
                a5 = __builtin_elementwise_fma(u1, etf[4*k+1], a5);
                a6 = __builtin_elementwise_fma(u2, etf[4*k+2], a6);
                a7 = __builtin_elementwise_fma(u3, etf[4*k+3], a7); break;
        case 4: a0 = __builtin_elementwise_fma(u0, etf[4*k+0], a0);
                a1 = __builtin_elementwise_fma(u1, etf[4*k+1], a1);
                a2 = __builtin_elementwise_fma(u2, etf[4*k+2], a2);
                a3 = __builtin_elementwise_fma(u3, etf[4*k+3], a3); break;
        case 5: a4 = __builtin_elementwise_fma(u0, etf[4*k+0], a4);
                a5 = __builtin_elementwise_fma(u1, etf[4*k+1], a5);
                a6 = __builtin_elementwise_fma(u2, etf[4*k+2], a6);
                a7 = __builtin_elementwise_fma(u3, etf[4*k+3], a7); break;
        case 6: a0 = __builtin_elementwise_fma(u0, etf[4*k+0], a0);
                a1 = __builtin_elementwise_fma(u1, etf[4*k+1], a1);
                a2 = __builtin_elementwise_fma(u2, etf[4*k+2], a2);
                a3 = __builtin_elementwise_fma(u3, etf[4*k+3], a3); break;
        default: a4 = __builtin_elementwise_fma(u0, etf[4*k+0], a4);
                 a5 = __builtin_elementwise_fma(u1, etf[4*k+1], a5);
                 a6 = __builtin_elementwise_fma(u2, etf[4*k+2], a6);
                 a7 = __builtin_elementwise_fma(u3, etf[4*k+3], a7); break;
      }
    }
    f32x2 s2 = ((a0 + a1) + (a2 + a3)) + ((a4 + a5) + (a6 + a7));
    float s = s2[0] + s2[1];
    p = s * ex;          // chain: reads -> fma tree -> mul. No trans, no max.
    S += LN_DAMP;
    r0 = r1; r1 = r2; r2 = r3; r3 = r4; r4 = r5; r5 = rn;
    if (c > 0 && t == cL - 1) {
      // warm-up discard: normalize to sum 1, reset scale (telescoping ref pt)
      float ssum = wave_sum_f32(p);
      p *= 1.0f / ssum;
      S = 0.f;
    } else if (((t - tb) & 7) == 7) {
      float r = wave_max_f32(p);  // every 8th step only: off the hot chain
      p *= 1.0f / r;
      S += __logf(r);
    }
  }

  float w_ = p;
  if (has_end) {
    float ev = endv[lane];
    if (bget(fen, lane, i32)) ev = IMPOSSIBLE;
    w_ = p * __expf(ev);  // e^{-10000} == 0: forbidden end states drop out
  }
  float zc = S + __logf(wave_sum_f32(w_));
  if (lane == 0) atomicAdd(out + b, zc);
}

// ---------------- z0: gold-path score, wave-per-row ballot version ----------
// (unchanged: ~12 us under the overhead model)
__global__ __launch_bounds__(256) void crf_z0(
    const float* __restrict__ em, const void* __restrict__ mask,
    const void* __restrict__ target, const float* __restrict__ trans,
    const float* __restrict__ startv, const float* __restrict__ endv,
    const void* __restrict__ ftr, const void* __restrict__ fst,
    const void* __restrict__ fen, float* __restrict__ out) {
  const int tid = threadIdx.x;
  const int lane = tid & 63;
  const int w = tid >> 6;
  const int b = blockIdx.x >> 4;
  const int q = blockIdx.x & 15;
  const bool i32 = bools_are_i32(mask);

  __shared__ int lred[4];
  __shared__ int tags[257];
  __shared__ float fred4[4];

  // ---- block-wide len[b] = sum(mask[b,:]) ----
  int ls = 0;
  if (i32) {
    const uint4* mv = (const uint4*)((const int*)mask + (size_t)b * TT);
#pragma unroll
    for (int k = 0; k < 4; ++k) {   // 1024 uint4 = 4096 ints
      uint4 u = mv[k * 256 + tid];
      ls += (int)(u.x + u.y + u.z + u.w);
    }
  } else {
    uint4 u = ((const uint4*)((const unsigned char*)mask + (size_t)b * TT))[tid];
    ls = bytesum4(u.x) + bytesum4(u.y) + bytesum4(u.z) + bytesum4(u.w);
  }
  ls = wave_sum_i32(ls);
  if (lane == 0) lred[w] = ls;

  // ---- tag extraction: wave w scans rows t0 + w*64 .. +63 ----
  const int t0 = q * 256;
  int mytag = 0;
  const size_t rb = ((size_t)b * TT + t0 + (size_t)w * 64) * NN + lane;
  if (i32) {
    const int* tg = (const int*)target + rb;
    for (int k = 0; k < 8; ++k) {
      int v[8];
#pragma unroll
      for (int j = 0; j < 8; ++j) v[j] = tg[(size_t)(k * 8 + j) * NN];
#pragma unroll
      for (int j = 0; j < 8; ++j) {
        unsigned long long bm = __ballot(v[j] != 0);
        int tv = __ffsll(bm) - 1;
        if (lane == k * 8 + j) mytag = tv;
      }
    }
  } else {
    const unsigned char* tg = (const unsigned char*)target + rb;
    for (int k = 0; k < 8; ++k) {
      int v[8];
#pragma unroll
      for (int j = 0; j < 8; ++j) v[j] = (int)tg[(size_t)(k * 8 + j) * NN];
#pragma unroll
      for (int j = 0; j < 8; ++j) {
        unsigned long long bm = __ballot(v[j] != 0);
        int tv = __ffsll(bm) - 1;
        if (lane == k * 8 + j) mytag = tv;
      }
    }
  }
  tags[tid + 1] = mytag;
  if (w == 0) {  // boundary row t0-1 for the block's first transition
    int rp = (t0 == 0) ? 0 : t0 - 1;
    int vv = i32 ? ((const int*)target)[((size_t)b * TT + rp) * NN + lane]
                 : (int)((const unsigned char*)
                       target)[((size_t)b * TT + rp) * NN + lane];
    unsigned long long bm = __ballot(vv != 0);
    int tv = __ffsll(bm) - 1;
    if (tid == 0) tags[0] = (t0 == 0) ? 0 : tv;
  }
  __syncthreads();  // publish lred + tags
  const int len = lred[0] + lred[1] + lred[2] + lred[3];

  const int t = t0 + tid;
  float contrib = 0.f;
  if (t < len) {
    int tg = tags[tid + 1];
    float emv = em[((size_t)b * TT + t) * NN + tg];
    if (t == 0) {
      float sv = startv[tg];
      if (bget(fst, tg, i32)) sv = IMPOSSIBLE;
      contrib = sv + emv;
    } else {
      int tp = tags[tid];
      float tv = trans[tp * NN + tg];
      if (bget(ftr, tp * NN + tg, i32)) tv = IMPOSSIBLE;
      contrib = tv + emv;
    }
    if (t == len - 1) {
      float evv = endv[tg];
      if (bget(fen, tg, i32)) evv = IMPOSSIBLE;
      contrib += evv;
    }
  }
  float wsum = wave_sum_f32(contrib);
  if (lane == 0) fred4[w] = wsum;
  __syncthreads();
  if (tid == 0)
    atomicAdd(out + b, -(fred4[0] + fred4[1] + fred4[2] + fred4[3]));
}

extern "C" void kernel_launch(void* const* d_in, const int* in_sizes, int n_in,
                              void* d_out, int out_size, void* d_ws,
                              size_t ws_size, hipStream_t stream) {
  const float* em = (const float*)d_in[0];
  const void* mask = d_in[1];
  const void* target = d_in[2];
  const float* trans = (const float*)d_in[3];
  const float* startv = (const float*)d_in[4];
  const float* endv = (const float*)d_in[5];
  const void* ftr = d_in[6];
  const void* fst = d_in[7];
  const void* fen = d_in[8];
  float* out = (float*)d_out;

  hipMemsetAsync(out, 0, BB * sizeof(float), stream);
  crf_z1<<<dim3(BB * KCH), dim3(64), 0, stream>>>(em, mask, trans, startv,
                                                  endv, ftr, fst, fen, out);
  crf_z0<<<dim3(BB * 16), dim3(256), 0, stream>>>(
      em, mask, target, trans, startv, endv, ftr, fst, fen, out);
}

// Round 13
// 222.163 us; speedup vs baseline: 1.3338x; 1.0063x over previous
//
#include <hip/hip_runtime.h>
#include <stdint.h>

#define IMPOSSIBLE -10000.0f
#define TT 4096
#define NN 64
#define BB 64
#define CHUNK 64            // paired: each wave runs chunks q and q+32
#define WARM 16             // R12-validated (0.38^15 ~ 5e-7 nats/boundary)
#define NI (WARM + CHUNK - 1)  // 79 unified iterations per wave

typedef _Float16 half2_t __attribute__((ext_vector_type(2)));

__device__ __forceinline__ float fdot2f(half2_t a, half2_t b, float c) {
#if __has_builtin(__builtin_amdgcn_fdot2)
  return __builtin_amdgcn_fdot2(a, b, c, false);
#else
  return c + (float)a[0] * (float)b[0] + (float)a[1] * (float)b[1];
#endif
}

// ---- bool-input dtype shim: harness may pass jnp.bool as int32 or uint8 ----
__device__ __forceinline__ bool bools_are_i32(const void* mask) {
  return ((const unsigned int*)mask)[0] == 1u;
}
__device__ __forceinline__ int bget(const void* p, int idx, bool i32) {
  return i32 ? ((const int*)p)[idx] : (int)((const unsigned char*)p)[idx];
}

// ---- DPP wave-64 reductions (VALU only) ----
__device__ __forceinline__ float wave_max_f32(float x) {
  int t;
#define STEP(ctrl)                                                            \
  t = __builtin_amdgcn_update_dpp(__float_as_int(x), __float_as_int(x), ctrl, \
                                  0xf, 0xf, false);                           \
  x = fmaxf(x, __int_as_float(t));
  STEP(0x111) STEP(0x112) STEP(0x114) STEP(0x118) STEP(0x142) STEP(0x143)
#undef STEP
  return __int_as_float(__builtin_amdgcn_readlane(__float_as_int(x), 63));
}

__device__ __forceinline__ float wave_sum_f32(float x) {
  int t;
#define STEP(ctrl)                                                         \
  t = __builtin_amdgcn_update_dpp(0, __float_as_int(x), ctrl, 0xf, 0xf,    \
                                  true);                                   \
  x += __int_as_float(t);
  STEP(0x111) STEP(0x112) STEP(0x114) STEP(0x118) STEP(0x142) STEP(0x143)
#undef STEP
  return __int_as_float(__builtin_amdgcn_readlane(__float_as_int(x), 63));
}

__device__ __forceinline__ int wave_sum_i32(int x) {
  int t;
#define STEP(ctrl)                                                      \
  t = __builtin_amdgcn_update_dpp(0, x, ctrl, 0xf, 0xf, true);          \
  x += t;
  STEP(0x111) STEP(0x112) STEP(0x114) STEP(0x118) STEP(0x142) STEP(0x143)
#undef STEP
  return __builtin_amdgcn_readlane(x, 63);
}

__device__ __forceinline__ float wave_lse(float x) {
  float m = wave_max_f32(x);
  float s = wave_sum_f32(__expf(x - m));
  return m + __logf(s);
}

__device__ __forceinline__ int bytesum4(unsigned int u) {
  return (int)((u * 0x01010101u) >> 24);  // bytes are 0/1, sum <= 4
}

// ---------------- z1: dual-chain per wave AT 2 waves/SIMD -------------------
// Measured law (R0-R12): z1 = iterations/SIMD x c_slot. Wave-overlap at
// 2w/SIMD is exactly 2.0x (R6/R12: slot 672 = latency 1343/2); in-wave dual-
// chain ILP packs 2 chain-steps into 1811cy (R9, 1w/SIMD). This round
// composes both: CHUNK=64 pairs (cA=q, cB=q+32) -> 2048 waves (2/SIMD), 79
// iterations each, 2 chain-steps per iteration. Same per-SIMD iteration
// count as R12 (158) but double the work per iteration.
// Body = R9 (harness-verified dual-chain, absmax 0.0) + validated deltas:
// WARM 16 (R12), no waitcnt asm (R10), pair mapping, launch_bounds(64,2).
__global__ __launch_bounds__(64, 2) void crf_z1(
    const float* __restrict__ em, const void* __restrict__ mask,
    const float* __restrict__ trans, const float* __restrict__ startv,
    const float* __restrict__ endv, const void* __restrict__ ftr,
    const void* __restrict__ fst, const void* __restrict__ fen,
    float* __restrict__ out) {
  const int lane = threadIdx.x;
  const int b = blockIdx.x >> 5;   // 32 chunk-pairs per batch
  const int q = blockIdx.x & 31;
  const bool i32 = bools_are_i32(mask);

  // len[b] = sum(mask[b, :])
  int ls = 0;
  if (i32) {
    const uint4* mv = (const uint4*)((const int*)mask + (size_t)b * TT);
#pragma unroll
    for (int k = 0; k < 16; ++k) {               // 1024 uint4 = 4096 ints
      uint4 w = mv[k * 64 + lane];
      ls += (int)(w.x + w.y + w.z + w.w);
    }
  } else {
    const uint4* mv = (const uint4*)((const unsigned char*)mask + (size_t)b * TT);
#pragma unroll
    for (int k = 0; k < 4; ++k) {                // 256 uint4 = 4096 bytes
      uint4 w = mv[k * 64 + lane];
      ls += bytesum4(w.x) + bytesum4(w.y) + bytesum4(w.z) + bytesum4(w.w);
    }
  }
  const int len = wave_sum_i32(ls);

  const int cA = q;              // chunks 0..31: LA+CHUNK <= 2048 <= len always
  const int cB = q + 32;         // chunks 32..63: may be partial or inactive
  const int LA = cA * CHUNK;
  const int LB = cB * CHUNK;
  const bool Bact = (LB < len);

  // ET[i][j] = exp(masked trans[i][j]); lane j holds column j as 32 f16 pairs
  half2_t et2[32];
#pragma unroll
  for (int i2 = 0; i2 < 32; ++i2) {
    int i0 = 2 * i2, i1 = 2 * i2 + 1;
    float t0 = trans[i0 * NN + lane];
    float t1 = trans[i1 * NN + lane];
    if (bget(ftr, i0 * NN + lane, i32)) t0 = IMPOSSIBLE;
    if (bget(ftr, i1 * NN + lane, i32)) t1 = IMPOSSIBLE;
    half2_t h;
    h[0] = (_Float16)__expf(t0);
    h[1] = (_Float16)__expf(t1);
    et2[i2] = h;
  }

  const float* emb = em + (size_t)b * TT * NN + lane;

  // chain A init
  float nA, SA = 0.f;
  int tloA;
  const int thiA = LA + CHUNK - 1;          // <= 2047 <= len-1 always
  if (cA == 0) {
    float sv = startv[lane];
    if (bget(fst, lane, i32)) sv = IMPOSSIBLE;
    nA = sv + emb[0];
    tloA = 1;
  } else {
    nA = emb[(size_t)(LA - WARM) * NN];     // arbitrary init; warm-up forgets
    tloA = LA - WARM + 1;
  }

  // chain B init (indices always memory-safe; results gated by Bact/thiB)
  float nB = emb[(size_t)(LB - WARM) * NN];
  float SB = 0.f;
  const int tloB = LB - WARM + 1;
  const int thiB = min(LB + CHUNK - 1, len - 1);  // < tloB when inactive

  __shared__ __align__(16) _Float16 pbuf[2][2][64];  // [chain][parity][64]

  // depth-4 em prefetch rings (one per chain); no barrier, no waitcnt asm ->
  // vmcnt stays counted across iterations.
  float rA0 = emb[(size_t)tloA * NN];
  float rA1 = emb[(size_t)min(tloA + 1, TT - 1) * NN];
  float rA2 = emb[(size_t)min(tloA + 2, TT - 1) * NN];
  float rA3 = emb[(size_t)min(tloA + 3, TT - 1) * NN];
  float rB0 = emb[(size_t)tloB * NN];
  float rB1 = emb[(size_t)min(tloB + 1, TT - 1) * NN];
  float rB2 = emb[(size_t)min(tloB + 2, TT - 1) * NN];
  float rB3 = emb[(size_t)min(tloB + 3, TT - 1) * NN];

  for (int i = 0; i < NI; ++i) {
    const int tA = tloA + i;
    const int tB = tloB + i;
    float rnA = emb[(size_t)min(tA + 4, TT - 1) * NN];  // prefetch
    float rnB = emb[(size_t)min(tB + 4, TT - 1) * NN];

    // front halves (independent -> interleave)
    float mA = wave_max_f32(nA);
    float mB = wave_max_f32(nB);
    float pA = __expf(nA - mA);
    float pB = __expf(nB - mB);
    const int par = i & 1;
    pbuf[0][par][lane] = (_Float16)pA;
    pbuf[1][par][lane] = (_Float16)pB;
    // same-wave DS in-order (R10-verified): no explicit waitcnt; the compiler
    // inserts the counted lgkmcnt before the first consuming fdot2.
    __builtin_amdgcn_sched_barrier(0);
    const uint4* pvA = (const uint4*)pbuf[0][par];
    const uint4* pvB = (const uint4*)pbuf[1][par];
    uint4 qaA[8], qaB[8];
#pragma unroll
    for (int k = 0; k < 8; ++k) qaA[k] = pvA[k];  // 16x ds_read_b128,
#pragma unroll
    for (int k = 0; k < 8; ++k) qaB[k] = pvB[k];  // one cluster
    __builtin_amdgcn_sched_barrier(0);
    float a0 = 0.f, a1 = 0.f, a2 = 0.f, a3 = 0.f;
    float b0 = 0.f, b1 = 0.f, b2 = 0.f, b3 = 0.f;
#pragma unroll
    for (int k = 0; k < 8; ++k) {
      a0 = fdot2f(__builtin_bit_cast(half2_t, qaA[k].x), et2[4 * k + 0], a0);
      a1 = fdot2f(__builtin_bit_cast(half2_t, qaA[k].y), et2[4 * k + 1], a1);
      a2 = fdot2f(__builtin_bit_cast(half2_t, qaA[k].z), et2[4 * k + 2], a2);
      a3 = fdot2f(__builtin_bit_cast(half2_t, qaA[k].w), et2[4 * k + 3], a3);
      b0 = fdot2f(__builtin_bit_cast(half2_t, qaB[k].x), et2[4 * k + 0], b0);
      b1 = fdot2f(__builtin_bit_cast(half2_t, qaB[k].y), et2[4 * k + 1], b1);
      b2 = fdot2f(__builtin_bit_cast(half2_t, qaB[k].z), et2[4 * k + 2], b2);
      b3 = fdot2f(__builtin_bit_cast(half2_t, qaB[k].w), et2[4 * k + 3], b3);
    }
    float sA = (a0 + a1) + (a2 + a3);
    float sB = (b0 + b1) + (b2 + b3);

    // act-gated updates (wave-uniform conditions -> cndmask, no divergence)
    const bool aAct = (tA <= thiA);
    const bool bAct = (tB <= thiB);
    nA = aAct ? (__logf(sA) + rA0) : nA;
    nB = bAct ? (__logf(sB) + rB0) : nB;
    SA += aAct ? mA : 0.f;
    SB += bAct ? mB : 0.f;
    rA0 = rA1; rA1 = rA2; rA2 = rA3; rA3 = rnA;
    rB0 = rB1; rB1 = rB2; rB2 = rB3; rB3 = rnB;
    if (i == WARM - 2) {  // t == cL-1 for both chains: discard warm-up scale
      if (cA > 0) SA = -wave_lse(nA);
      if (Bact) SB = -wave_lse(nB);
    }
  }

  float ev = endv[lane];
  if (bget(fen, lane, i32)) ev = IMPOSSIBLE;
  const bool hasEndA = (len <= LA + CHUNK);  // only cA=31 & len==2048
  float zcA = hasEndA ? wave_lse(nA + ev) : wave_lse(nA);
  float res = SA + zcA;
  if (Bact) {
    const bool hasEndB = (len <= LB + CHUNK);
    float zcB = hasEndB ? wave_lse(nB + ev) : wave_lse(nB);
    res += SB + zcB;
  }
  if (lane == 0) atomicAdd(out + b, res);
}

// ---------------- z0: gold-path score, wave-per-row ballot version ----------
// (unchanged: ~12 us under the overhead model)
__global__ __launch_bounds__(256) void crf_z0(
    const float* __restrict__ em, const void* __restrict__ mask,
    const void* __restrict__ target, const float* __restrict__ trans,
    const float* __restrict__ startv, const float* __restrict__ endv,
    const void* __restrict__ ftr, const void* __restrict__ fst,
    const void* __restrict__ fen, float* __restrict__ out) {
  const int tid = threadIdx.x;
  const int lane = tid & 63;
  const int w = tid >> 6;
  const int b = blockIdx.x >> 4;
  const int q = blockIdx.x & 15;
  const bool i32 = bools_are_i32(mask);

  __shared__ int lred[4];
  __shared__ int tags[257];
  __shared__ float fred4[4];

  // ---- block-wide len[b] = sum(mask[b,:]) ----
  int ls = 0;
  if (i32) {
    const uint4* mv = (const uint4*)((const int*)mask + (size_t)b * TT);
#pragma unroll
    for (int k = 0; k < 4; ++k) {   // 1024 uint4 = 4096 ints
      uint4 u = mv[k * 256 + tid];
      ls += (int)(u.x + u.y + u.z + u.w);
    }
  } else {
    uint4 u = ((const uint4*)((const unsigned char*)mask + (size_t)b * TT))[tid];
    ls = bytesum4(u.x) + bytesum4(u.y) + bytesum4(u.z) + bytesum4(u.w);
  }
  ls = wave_sum_i32(ls);
  if (lane == 0) lred[w] = ls;

  // ---- tag extraction: wave w scans rows t0 + w*64 .. +63 ----
  const int t0 = q * 256;
  int mytag = 0;
  const size_t rb = ((size_t)b * TT + t0 + (size_t)w * 64) * NN + lane;
  if (i32) {
    const int* tg = (const int*)target + rb;
    for (int k = 0; k < 8; ++k) {
      int v[8];
#pragma unroll
      for (int j = 0; j < 8; ++j) v[j] = tg[(size_t)(k * 8 + j) * NN];
#pragma unroll
      for (int j = 0; j < 8; ++j) {
        unsigned long long bm = __ballot(v[j] != 0);
        int tv = __ffsll(bm) - 1;
        if (lane == k * 8 + j) mytag = tv;
      }
    }
  } else {
    const unsigned char* tg = (const unsigned char*)target + rb;
    for (int k = 0; k < 8; ++k) {
      int v[8];
#pragma unroll
      for (int j = 0; j < 8; ++j) v[j] = (int)tg[(size_t)(k * 8 + j) * NN];
#pragma unroll
      for (int j = 0; j < 8; ++j) {
        unsigned long long bm = __ballot(v[j] != 0);
        int tv = __ffsll(bm) - 1;
        if (lane == k * 8 + j) mytag = tv;
      }
    }
  }
  tags[tid + 1] = mytag;
  if (w == 0) {  // boundary row t0-1 for the block's first transition
    int rp = (t0 == 0) ? 0 : t0 - 1;
    int vv = i32 ? ((const int*)target)[((size_t)b * TT + rp) * NN + lane]
                 : (int)((const unsigned char*)
                       target)[((size_t)b * TT + rp) * NN + lane];
    unsigned long long bm = __ballot(vv != 0);
    int tv = __ffsll(bm) - 1;
    if (tid == 0) tags[0] = (t0 == 0) ? 0 : tv;
  }
  __syncthreads();  // publish lred + tags
  const int len = lred[0] + lred[1] + lred[2] + lred[3];

  const int t = t0 + tid;
  float contrib = 0.f;
  if (t < len) {
    int tg = tags[tid + 1];
    float emv = em[((size_t)b * TT + t) * NN + tg];
    if (t == 0) {
      float sv = startv[tg];
      if (bget(fst, tg, i32)) sv = IMPOSSIBLE;
      contrib = sv + emv;
    } else {
      int tp = tags[tid];
      float tv = trans[tp * NN + tg];
      if (bget(ftr, tp * NN + tg, i32)) tv = IMPOSSIBLE;
      contrib = tv + emv;
    }
    if (t == len - 1) {
      float evv = endv[tg];
      if (bget(fen, tg, i32)) evv = IMPOSSIBLE;
      contrib += evv;
    }
  }
  float wsum = wave_sum_f32(contrib);
  if (lane == 0) fred4[w] = wsum;
  __syncthreads();
  if (tid == 0)
    atomicAdd(out + b, -(fred4[0] + fred4[1] + fred4[2] + fred4[3]));
}

extern "C" void kernel_launch(void* const* d_in, const int* in_sizes, int n_in,
                              void* d_out, int out_size, void* d_ws,
                              size_t ws_size, hipStream_t stream) {
  const float* em = (const float*)d_in[0];
  const void* mask = d_in[1];
  const void* target = d_in[2];
  const float* trans = (const float*)d_in[3];
  const float* startv = (const float*)d_in[4];
  const float* endv = (const float*)d_in[5];
  const void* ftr = d_in[6];
  const void* fst = d_in[7];
  const void* fen = d_in[8];
  float* out = (float*)d_out;

  hipMemsetAsync(out, 0, BB * sizeof(float), stream);
  crf_z1<<<dim3(BB * 32), dim3(64), 0, stream>>>(em, mask, trans, startv,
                                                 endv, ftr, fst, fen, out);
  crf_z0<<<dim3(BB * 16), dim3(256), 0, stream>>>(
      em, mask, target, trans, startv, endv, ftr, fst, fen, out);
}